// Round 13
// baseline (765.634 us; speedup 1.0000x reference)
//
#include <hip/hip_runtime.h>

#define HH 512
#define WW 512
#define NB 8
#define HWSZ (HH * WW)
#define PW 516   // padded row stride (cols 0..515; image at 1..512; col 513 zero; 514/515 junk)
#define PROWS 514  // rows 0..513; image rows at 1..512

typedef float f32x4 __attribute__((ext_vector_type(4)));
typedef float f32x16 __attribute__((ext_vector_type(16)));
typedef short bf16x8 __attribute__((ext_vector_type(8)));

__device__ __forceinline__ unsigned short f2bf(float f) {
  union { float f; unsigned u; } v; v.f = f;
  unsigned r = v.u + 0x7FFFu + ((v.u >> 16) & 1u);
  return (unsigned short)(r >> 16);
}
__device__ __forceinline__ float bf2f(unsigned u16) {
  union { unsigned u; float f; } v; v.u = u16 << 16;
  return v.f;
}

// async global->LDS copy, 16B per lane; dst wave-uniform base + lane*16
__device__ __forceinline__ void gload16(const uint4* g, uint4* l) {
  __builtin_amdgcn_global_load_lds((__attribute__((address_space(1))) void*)g,
                                   (__attribute__((address_space(3))) void*)l, 16, 0, 0);
}

// shorts per padded image plane (chunk-major: [row][chunk][col] 16B chunks)
#define PS1 ((size_t)PROWS * PW * 32)
#define PS2 ((size_t)PROWS * PW * 64)
#define NZ1 (2 * 4 * PW * 8 + 512 * 4 * 16)
#define NZ2 (2 * 8 * PW * 8 + 512 * 8 * 16)

__device__ __forceinline__ void zp(unsigned short* buf, int NCH, int i) {
  int rowShorts = NCH * PW * 8;
  if (i < 2 * rowShorts) {
    size_t r = (i < rowShorts) ? 0 : 513;
    int j = i % rowShorts;
    buf[r * rowShorts + j] = 0;
    return;
  }
  i -= 2 * rowShorts;
  int perRow = NCH * 16;
  int r = 1 + i / perRow;
  int j = i % perRow;
  int ch = j >> 4;
  int c = (j & 8) ? 513 : 0;
  int e = j & 7;
  buf[(((size_t)r * NCH + ch) * PW + c) * 8 + e] = 0;
}

// ---- fused one-time prep ----
// wp2 fragment order: [tap][ks][mt][lane][8]; wp3 fragment order: [tap][ks][lane][8].
__global__ __launch_bounds__(256) void k_prep(const float* __restrict__ w2,
                                              const float* __restrict__ w3,
                                              const float* __restrict__ h0,
                                              const float* __restrict__ h1,
                                              const float* __restrict__ h2,
                                              unsigned short* __restrict__ wp2,
                                              unsigned short* __restrict__ wp3,
                                              unsigned short* __restrict__ wph,
                                              unsigned short* __restrict__ t1,
                                              unsigned short* __restrict__ t2,
                                              float* __restrict__ S) {
  int i = blockIdx.x * 256 + threadIdx.x;
  const int N1 = 9 * 64 * 32;
  const int N2 = N1 + 9 * 32 * 64;
  const int N3 = N2 + 9 * 16 * 32;
  const int N4 = N3 + 4 * NZ1;
  const int N5 = N4 + 4 * NZ2;
  const int N6 = N5 + 128;
  if (i < N1) {  // conv2 weights, fragment order: j8|lane|mt|ks|tap
    int j8 = i & 7;
    int lane = (i >> 3) & 63;
    int mt = (i >> 9) & 1;
    int ks = (i >> 10) & 1;
    int tap = i >> 11;
    int l31 = lane & 31, h16 = lane >> 5;
    int oc = mt * 32 + l31;
    int ic = ks * 16 + h16 * 8 + j8;
    wp2[i] = f2bf(w2[(oc * 32 + ic) * 9 + tap]);
  } else if (i < N2) {  // conv3 weights, fragment order: j8|lane|ks|tap
    int j = i - N1;
    int j8 = j & 7;
    int lane = (j >> 3) & 63;
    int ks = (j >> 9) & 3;
    int tap = j >> 11;
    int l31 = lane & 31, h16 = lane >> 5;
    int ic = ks * 16 + h16 * 8 + j8;
    wp3[j] = f2bf(w3[(l31 * 64 + ic) * 9 + tap]);
  } else if (i < N3) {  // heads -> [9][16][32], oc 12..15 zero
    int j = i - N2;
    int ic = j & 31, t = j >> 5, oc = t & 15, k = t >> 4;
    float v = 0.f;
    if (oc < 12) {
      const float* w = oc < 4 ? h0 : (oc < 8 ? h1 : h2);
      v = w[((oc & 3) * 32 + ic) * 9 + k];
    }
    wph[j] = f2bf(v);
  } else if (i < N4) {
    int j = i - N3;
    zp(t1 + (size_t)(j / NZ1) * PS1, 4, j % NZ1);
  } else if (i < N5) {
    int j = i - N4;
    zp(t2 + (size_t)(j / NZ2) * PS2, 8, j % NZ2);
  } else if (i < N6) {
    S[i - N5] = 0.f;
  }
}

// ---- conv1: 1->32, VALU, fp32 in -> padded chunk-major bf16 out ----
__global__ __launch_bounds__(256) void k_conv1(const float* __restrict__ x,
                                               const float* __restrict__ w,
                                               const float* __restrict__ bias,
                                               const float* __restrict__ a_ptr,
                                               unsigned short* __restrict__ out) {
  const float* xp = x + (size_t)blockIdx.z * HWSZ;
  uint4* out4 = (uint4*)(out + (size_t)blockIdx.z * PS1);
  int pix = blockIdx.x * 256 + threadIdx.x;
  int h = pix >> 9, wc = pix & 511;
  float t[9];
#pragma unroll
  for (int dh = 0; dh < 3; dh++)
#pragma unroll
    for (int dw = 0; dw < 3; dw++) {
      int hh = h + dh - 1, ww = wc + dw - 1;
      t[dh * 3 + dw] =
          (hh >= 0 && hh < HH && ww >= 0 && ww < WW) ? xp[hh * WW + ww] : 0.f;
    }
  float a = a_ptr[0];
  unsigned pk[16];
#pragma unroll
  for (int oc = 0; oc < 32; oc++) {
    float s = bias[oc];
#pragma unroll
    for (int k = 0; k < 9; k++) s = fmaf(w[oc * 9 + k], t[k], s);
    s = s >= 0.f ? s : a * s;
    unsigned short b = f2bf(s);
    if (oc & 1)
      pk[oc >> 1] |= ((unsigned)b) << 16;
    else
      pk[oc >> 1] = b;
  }
#pragma unroll
  for (int q = 0; q < 4; q++)
    out4[((size_t)(h + 1) * 4 + q) * PW + (wc + 1)] = *(uint4*)&pk[q * 4];
}

// ---- conv2 (32->64): single-barrier 10-slot ring + fragment-order LDS weights ----
__global__ __launch_bounds__(256, 2) void k_convm2(const unsigned short* __restrict__ in,
                                                   const unsigned short* __restrict__ wp,
                                                   const float* __restrict__ bias,
                                                   const float* __restrict__ a_ptr,
                                                   unsigned short* __restrict__ out) {
  __shared__ __align__(16) short ring[10 * 4 * 68 * 8];  // 43520 B
  __shared__ __align__(16) short wlds[9 * 2 * 2 * 64 * 8];  // 36864 B, fragment order
  const int tid = threadIdx.x, lane = tid & 63, wid = tid >> 6;
  const int l31 = lane & 31, h16 = lane >> 5;
  const int c0 = blockIdx.x * 64;
  const int R0 = blockIdx.y * 32;
  const uint4* in4 = (const uint4*)(in + (size_t)blockIdx.z * PS1);
  unsigned short* outz = out + (size_t)blockIdx.z * PS2;
  uint4* ring4 = (uint4*)ring;
  uint4* wl4 = (uint4*)wlds;
  const uint4* wp4 = (const uint4*)wp;

  for (int sg = wid; sg < 36; sg += 4)
    gload16(wp4 + sg * 64 + lane, wl4 + sg * 64);

  auto load_rows = [&](int rfirst, int nrows) {
    int nseg = nrows * 4;
    for (int sg = wid; sg < nseg; sg += 4) {
      int rr = rfirst + (sg >> 2);
      int ch = sg & 3;
      const uint4* src = in4 + (size_t)(rr * 4 + ch) * PW + c0;
      uint4* dst = ring4 + ((rr % 10) * 4 + ch) * 68;
      gload16(src + lane, dst);
      gload16(src + 4 + lane, dst + 4);
    }
  };

  const float alpha = a_ptr[0];
  load_rows(R0, 6);

  for (int k = 0; k < 8; ++k) {
    const int rb = R0 + 4 * k;
    __syncthreads();
    if (k < 7) load_rows(rb + 6, 4);

    f32x16 acc[2][2];
#pragma unroll
    for (int nt = 0; nt < 2; nt++)
#pragma unroll
      for (int mt = 0; mt < 2; mt++)
#pragma unroll
        for (int j = 0; j < 16; j++) acc[nt][mt][j] = 0.f;

#pragma unroll
    for (int dh = 0; dh < 3; dh++) {
      bf16x8 af[3][2][2];
#pragma unroll
      for (int dw = 0; dw < 3; dw++)
#pragma unroll
        for (int ks = 0; ks < 2; ks++)
#pragma unroll
          for (int mt = 0; mt < 2; mt++)
            af[dw][ks][mt] = *(const bf16x8*)(
                wlds + ((((size_t)((dh * 3 + dw) * 2 + ks) * 2 + mt) * 64 + lane) * 8));
      const short* lrow = ring + (size_t)(((rb + wid + dh) % 10) * 4) * 68 * 8;
#pragma unroll
      for (int dw = 0; dw < 3; dw++) {
        const int pl0 = l31 + dw, pl1 = 32 + l31 + dw;
#pragma unroll
        for (int ks = 0; ks < 2; ks++) {
          const int blk = ks * 2 + h16;
          bf16x8 b0 = *(const bf16x8*)(lrow + (blk * 68 + pl0) * 8);
          bf16x8 b1 = *(const bf16x8*)(lrow + (blk * 68 + pl1) * 8);
#pragma unroll
          for (int mt = 0; mt < 2; mt++)
            acc[0][mt] = __builtin_amdgcn_mfma_f32_32x32x16_bf16(af[dw][ks][mt],
                                                                 b0, acc[0][mt], 0, 0, 0);
#pragma unroll
          for (int mt = 0; mt < 2; mt++)
            acc[1][mt] = __builtin_amdgcn_mfma_f32_32x32x16_bf16(af[dw][ks][mt],
                                                                 b1, acc[1][mt], 0, 0, 0);
        }
      }
    }

    const int orow = rb + wid + 1;
    uint2* o2 = (uint2*)outz;
#pragma unroll
    for (int nt = 0; nt < 2; nt++) {
      const int ocol = c0 + nt * 32 + l31 + 1;
#pragma unroll
      for (int mt = 0; mt < 2; mt++)
#pragma unroll
        for (int g = 0; g < 4; g++) {
          int oc0 = mt * 32 + g * 8 + h16 * 4;
          f32x4 bv = *(const f32x4*)(bias + oc0);
          float v[4];
#pragma unroll
          for (int j = 0; j < 4; j++) {
            float s = acc[nt][mt][g * 4 + j] + bv[j];
            v[j] = s >= 0.f ? s : alpha * s;
          }
          uint2 pk;
          pk.x = (unsigned)f2bf(v[0]) | ((unsigned)f2bf(v[1]) << 16);
          pk.y = (unsigned)f2bf(v[2]) | ((unsigned)f2bf(v[3]) << 16);
          size_t idx16 = ((size_t)orow * 8 + (mt * 4 + g)) * PW + ocol;
          o2[idx16 * 2 + h16] = pk;
        }
    }
  }
}

// ---- conv3 (64->32): split-IC 8-wave blocks, register weights, 8-slot ring ----
// Block: 512 thr = 4 row-waves x 2 ic-halves; 32 cols x 32 rows; partials summed via LDS.
__global__ __launch_bounds__(512, 6) void k_convm3(const unsigned short* __restrict__ in,
                                                   const unsigned short* __restrict__ wp,
                                                   const float* __restrict__ bias,
                                                   const float* __restrict__ a_ptr,
                                                   unsigned short* __restrict__ out) {
  __shared__ __align__(16) short ring[8 * 8 * 36 * 8];   // 36864 B
  __shared__ __align__(16) float red[4 * 4 * 64 * 4];    // 16384 B: [row][g][lane][4]
  const int tid = threadIdx.x, lane = tid & 63, wid = tid >> 6;
  const int l31 = lane & 31, h16 = lane >> 5;
  const int rw = wid & 3;      // row-wave
  const int ih = wid >> 2;     // ic half (0: ic 0..31, 1: ic 32..63)
  const int c0 = blockIdx.x * 32;
  const int R0 = blockIdx.y * 32;
  const uint4* in4 = (const uint4*)(in + (size_t)blockIdx.z * PS2);
  unsigned short* outz = out + (size_t)blockIdx.z * PS1;
  uint4* ring4 = (uint4*)ring;
  f32x4* red4 = (f32x4*)red;

  // register-resident weights for this ic half: 18 frags = 72 VGPR, no spill
  bf16x8 af[9][2];
#pragma unroll
  for (int t = 0; t < 9; t++)
#pragma unroll
    for (int kk = 0; kk < 2; kk++)
      af[t][kk] = *(const bf16x8*)(wp + ((size_t)(t * 4 + ih * 2 + kk) * 64 + lane) * 8);

  auto load_rows = [&](int rfirst, int nrows) {
    int nseg = nrows * 8;
    for (int sg = wid; sg < nseg; sg += 8) {
      int rr = rfirst + (sg >> 3);
      int ch = sg & 7;
      const uint4* src = in4 + (size_t)(rr * 8 + ch) * PW + c0;
      uint4* dst = ring4 + ((rr & 7) * 8 + ch) * 36;
      if (lane < 36) gload16(src + lane, dst);  // 36 px incl. +2 halo
    }
  };

  const float alpha = a_ptr[0];
  load_rows(R0, 6);

  for (int k = 0; k < 8; ++k) {
    const int rb = R0 + 4 * k;
    __syncthreads();                 // drains DMAs; prev iter's red reads done
    if (k < 7) load_rows(rb + 6, 2);

    f32x16 acc;
#pragma unroll
    for (int j = 0; j < 16; j++) acc[j] = 0.f;

#pragma unroll
    for (int dh = 0; dh < 3; dh++) {
      const short* lrow = ring + (size_t)(((rb + rw + dh) & 7) * 8) * 36 * 8;
#pragma unroll
      for (int dw = 0; dw < 3; dw++) {
        const int pl = l31 + dw;
#pragma unroll
        for (int kk = 0; kk < 2; kk++) {
          const int blk = (ih * 2 + kk) * 2 + h16;
          bf16x8 b = *(const bf16x8*)(lrow + (blk * 36 + pl) * 8);
          acc = __builtin_amdgcn_mfma_f32_32x32x16_bf16(af[dh * 3 + dw][kk], b, acc,
                                                        0, 0, 0);
        }
      }
    }

    // half-1 publishes partials (canonical 16B/lane layout, conflict-free)
    if (ih == 1) {
#pragma unroll
      for (int g = 0; g < 4; g++) {
        f32x4 v = {acc[g * 4 + 0], acc[g * 4 + 1], acc[g * 4 + 2], acc[g * 4 + 3]};
        red4[(rw * 4 + g) * 64 + lane] = v;
      }
    }
    __syncthreads();                 // red visible; slots rb,rb+1 free
    if (k < 7) load_rows(rb + 8, 2);

    if (ih == 0) {
      const int orow = rb + rw + 1;
      const int ocol = c0 + l31 + 1;
      uint2* o2 = (uint2*)outz;
#pragma unroll
      for (int g = 0; g < 4; g++) {
        f32x4 p = red4[(rw * 4 + g) * 64 + lane];
        int oc0 = g * 8 + h16 * 4;
        f32x4 bv = *(const f32x4*)(bias + oc0);
        float v[4];
#pragma unroll
        for (int j = 0; j < 4; j++) {
          float s = acc[g * 4 + j] + p[j] + bv[j];
          v[j] = s >= 0.f ? s : alpha * s;
        }
        uint2 pk;
        pk.x = (unsigned)f2bf(v[0]) | ((unsigned)f2bf(v[1]) << 16);
        pk.y = (unsigned)f2bf(v[2]) | ((unsigned)f2bf(v[3]) << 16);
        size_t idx16 = ((size_t)orow * 4 + g) * PW + ocol;
        o2[idx16 * 2 + h16] = pk;
      }
    }
  }
}

// ---- fused 3-head conv 32->16(12 real): strip-marching, gload16 staging ----
__global__ __launch_bounds__(256, 2) void k_headm(const unsigned short* __restrict__ in,
                                                  const unsigned short* __restrict__ wp,
                                                  const float* __restrict__ hb0,
                                                  const float* __restrict__ hb1,
                                                  const float* __restrict__ hb2,
                                                  unsigned short* __restrict__ pre,
                                                  float* __restrict__ S) {
  __shared__ __align__(16) short lds[8 * 4 * 68 * 8];  // 34816 B
  __shared__ float part[4][4][4];
  const int tid = threadIdx.x, lane = tid & 63, wid = tid >> 6;
  const int l15 = lane & 15, q = lane >> 4;
  const int c0 = blockIdx.x * 64;
  const int R0 = blockIdx.y * 32;
  const uint4* in4 = (const uint4*)(in + (size_t)blockIdx.z * PS1);
  float* Sz = S + blockIdx.z * 16;
  uint4* lds4 = (uint4*)lds;

  bf16x8 af[9];
#pragma unroll
  for (int k9 = 0; k9 < 9; k9++)
    af[k9] = *(const bf16x8*)(wp + (size_t)(k9 * 16 + l15) * 32 + q * 8);

  float bs[4];
#pragma unroll
  for (int r = 0; r < 4; r++) {
    int oc = q * 4 + r;
    bs[r] = oc < 4 ? hb0[oc] : (oc < 8 ? hb1[oc - 4] : (oc < 12 ? hb2[oc - 8] : 0.f));
  }
  unsigned short* prehq = pre + ((size_t)(q * 4 + blockIdx.z) * HWSZ) * 4;

  auto load_rows = [&](int rfirst, int nrows) {
    int nseg = nrows * 4;
    for (int sg = wid; sg < nseg; sg += 4) {
      int rr = rfirst + (sg >> 2);
      int ch = sg & 3;
      const uint4* src = in4 + (size_t)(rr * 4 + ch) * PW + c0;
      uint4* dst = lds4 + ((rr & 7) * 4 + ch) * 68;
      gload16(src + lane, dst);
      gload16(src + 4 + lane, dst + 4);
    }
  };

  load_rows(R0, 6);
  float csum[4] = {0.f, 0.f, 0.f, 0.f};

  for (int k = 0; k < 8; ++k) {
    const int rb = R0 + 4 * k;
    __syncthreads();
    if (k < 7) load_rows(rb + 6, 2);

    f32x4 acc[4];
#pragma unroll
    for (int nt = 0; nt < 4; nt++)
#pragma unroll
      for (int j = 0; j < 4; j++) acc[nt][j] = 0.f;

#pragma unroll
    for (int dh = 0; dh < 3; dh++) {
      const short* lrow = lds + (size_t)(((rb + wid + dh) & 7) * 4) * 68 * 8;
#pragma unroll
      for (int dw = 0; dw < 3; dw++) {
        bf16x8 a = af[dh * 3 + dw];
#pragma unroll
        for (int nt = 0; nt < 4; nt++) {
          int pl = nt * 16 + l15 + dw;
          bf16x8 b = *(const bf16x8*)(lrow + (q * 68 + pl) * 8);
          acc[nt] = __builtin_amdgcn_mfma_f32_16x16x32_bf16(a, b, acc[nt], 0, 0, 0);
        }
      }
    }

    const int orow = rb + wid;
#pragma unroll
    for (int nt = 0; nt < 4; nt++) {
      int pix = orow * 512 + c0 + nt * 16 + l15;
      float v[4];
#pragma unroll
      for (int r = 0; r < 4; r++) {
        v[r] = acc[nt][r] + bs[r];
        csum[r] += v[r];
      }
      uint2 pk;
      pk.x = (unsigned)f2bf(v[0]) | ((unsigned)f2bf(v[1]) << 16);
      pk.y = (unsigned)f2bf(v[2]) | ((unsigned)f2bf(v[3]) << 16);
      *(uint2*)(prehq + (size_t)pix * 4) = pk;
    }
    __syncthreads();
    if (k < 7) load_rows(rb + 8, 2);
  }

#pragma unroll
  for (int d = 1; d < 16; d <<= 1)
#pragma unroll
    for (int r = 0; r < 4; r++) csum[r] += __shfl_xor(csum[r], d, 64);
  if (l15 == 0)
#pragma unroll
    for (int r = 0; r < 4; r++) part[wid][q][r] = csum[r];
  __syncthreads();
  if (tid < 12) {
    int oc = tid;
    float s = part[0][oc >> 2][oc & 3] + part[1][oc >> 2][oc & 3] +
              part[2][oc >> 2][oc & 3] + part[3][oc >> 2][oc & 3];
    atomicAdd(&Sz[oc], s);
  }
}

// ---- fused: gate + 3 box blurs + softmax(gate*pre) + weighted combine ----
#define BT 32
#define RAD 12
#define SRCT (BT + 2 * RAD)  // 56
__global__ __launch_bounds__(256) void k_blurcombine(const float* __restrict__ src,
                                                     const unsigned short* __restrict__ preh,
                                                     const float* __restrict__ S4,
                                                     const float* __restrict__ wa,
                                                     const float* __restrict__ wb,
                                                     float* __restrict__ dst) {
  __shared__ float tile[SRCT][SRCT];
  __shared__ float hs[3][SRCT][BT];
  __shared__ float g[4];
  const float* srcz = src + (size_t)blockIdx.z * HWSZ;
  const unsigned short* prez = preh + (size_t)blockIdx.z * HWSZ * 4;
  const float* S4z = S4 + blockIdx.z * 16;
  float* dstz = dst + (size_t)blockIdx.z * HWSZ;
  int h0 = blockIdx.y * BT - RAD, w0 = blockIdx.x * BT - RAD;
  if (threadIdx.x < 4) {
    int o = threadIdx.x;
    float m[4], ga[4];
#pragma unroll
    for (int c = 0; c < 4; c++) m[c] = S4z[c] * (1.0f / (float)HWSZ);
#pragma unroll
    for (int c = 0; c < 4; c++) {
      float s = 0.f;
#pragma unroll
      for (int j = 0; j < 4; j++) s = fmaf(wa[c * 4 + j], m[j], s);
      ga[c] = fmaxf(s, 0.f);
    }
    float s2 = 0.f;
#pragma unroll
    for (int c = 0; c < 4; c++) s2 = fmaf(wb[o * 4 + c], ga[c], s2);
    g[o] = 1.f / (1.f + expf(-s2));
  }
  for (int idx = threadIdx.x; idx < SRCT * SRCT; idx += 256) {
    int r = idx / SRCT, c = idx % SRCT;
    int hh = h0 + r, ww = w0 + c;
    float v = 0.f;
    if (hh >= 0 && hh < HH && ww >= 0 && ww < WW) v = srcz[hh * WW + ww];
    tile[r][c] = v;
  }
  __syncthreads();
  for (int idx = threadIdx.x; idx < SRCT * BT; idx += 256) {
    int r = idx / BT, j = idx % BT;
    int cc = j + RAD;
    float s5 = 0.f;
#pragma unroll
    for (int d = -2; d <= 2; d++) s5 += tile[r][cc + d];
    float s15 = s5;
#pragma unroll
    for (int d = 3; d <= 7; d++) s15 += tile[r][cc + d] + tile[r][cc - d];
    float s25 = s15;
#pragma unroll
    for (int d = 8; d <= 12; d++) s25 += tile[r][cc + d] + tile[r][cc - d];
    hs[0][r][j] = s5;
    hs[1][r][j] = s15;
    hs[2][r][j] = s25;
  }
  __syncthreads();
  for (int p = threadIdx.x; p < BT * BT; p += 256) {
    int i = p / BT, j = p % BT;
    int rr = i + RAD;
    float b1 = 0.f;
#pragma unroll
    for (int d = -2; d <= 2; d++) b1 += hs[0][rr + d][j];
    float b2 = 0.f;
#pragma unroll
    for (int d = -7; d <= 7; d++) b2 += hs[1][rr + d][j];
    float b3 = 0.f;
#pragma unroll
    for (int d = -12; d <= 12; d++) b3 += hs[2][rr + d][j];
    b1 *= (1.f / 25.f);
    b2 *= (1.f / 225.f);
    b3 *= (1.f / 625.f);
    float b0 = tile[rr][j + RAD];
    int y = blockIdx.y * BT + i, x = blockIdx.x * BT + j;
    int pix = y * WW + x;
    uint2 pk = *(const uint2*)(prez + (size_t)pix * 4);
    float v[4];
    v[0] = bf2f(pk.x & 0xffffu) * g[0];
    v[1] = bf2f(pk.x >> 16) * g[1];
    v[2] = bf2f(pk.y & 0xffffu) * g[2];
    v[3] = bf2f(pk.y >> 16) * g[3];
    float mx = fmaxf(fmaxf(v[0], v[1]), fmaxf(v[2], v[3]));
    float e0 = expf(v[0] - mx), e1 = expf(v[1] - mx), e2 = expf(v[2] - mx),
          e3 = expf(v[3] - mx);
    float inv = 1.f / (e0 + e1 + e2 + e3);
    dstz[pix] = (e0 * b0 + e1 * b1 + e2 * b2 + e3 * b3) * inv;
  }
}

extern "C" void kernel_launch(void* const* d_in, const int* in_sizes, int n_in,
                              void* d_out, int out_size, void* d_ws, size_t ws_size,
                              hipStream_t stream) {
  const float* x = (const float*)d_in[0];
  const float* w1 = (const float*)d_in[1];
  const float* b1 = (const float*)d_in[2];
  const float* a1 = (const float*)d_in[3];
  const float* w2 = (const float*)d_in[4];
  const float* b2 = (const float*)d_in[5];
  const float* a2 = (const float*)d_in[6];
  const float* w3 = (const float*)d_in[7];
  const float* b3 = (const float*)d_in[8];
  const float* a3 = (const float*)d_in[9];
  const float* hw[3] = {(const float*)d_in[10], (const float*)d_in[14], (const float*)d_in[18]};
  const float* hb[3] = {(const float*)d_in[11], (const float*)d_in[15], (const float*)d_in[19]};
  const float* caa[3] = {(const float*)d_in[12], (const float*)d_in[16], (const float*)d_in[20]};
  const float* cab[3] = {(const float*)d_in[13], (const float*)d_in[17], (const float*)d_in[21]};

  char* base = (char*)d_ws;
  size_t off = 0;
  auto alloc = [&](size_t bytes) {
    char* p = base + off;
    off = (off + bytes + 63) & ~(size_t)63;
    return p;
  };
  unsigned short* t1 = (unsigned short*)alloc(4 * PS1 * 2);          // 67.9 MB
  unsigned short* t2 = (unsigned short*)alloc(4 * PS2 * 2);          // 135.8 MB
  unsigned short* pre = (unsigned short*)alloc(16 * (size_t)HWSZ * 4 * 2);  // 32 MB planar
  unsigned short* wp2 = (unsigned short*)alloc(9 * 64 * 32 * 2);
  unsigned short* wp3 = (unsigned short*)alloc(9 * 64 * 32 * 2);
  unsigned short* wph = (unsigned short*)alloc(9 * 16 * 32 * 2);
  float* out1 = (float*)alloc(4 * (size_t)HWSZ * 4);                 // 4 MB
  float* out2 = (float*)alloc(4 * (size_t)HWSZ * 4);                 // 4 MB
  float* S = (float*)alloc(8 * 16 * 4);

  dim3 blk(256);
  {
    int total = 9 * 64 * 32 + 9 * 32 * 64 + 9 * 16 * 32 + 4 * NZ1 + 4 * NZ2 + 128;
    k_prep<<<(total + 255) / 256, blk, 0, stream>>>(w2, w3, hw[0], hw[1], hw[2], wp2,
                                                    wp3, wph, t1, t2, S);
  }

  dim3 gc1(1024, 1, 4);
  dim3 gconv(8, 16, 4);     // 64-col strips x 32-row chunks x 4 images
  dim3 gconv3(16, 16, 4);   // 32-col strips x 32-row chunks x 4 images
  dim3 gbc(WW / BT, HH / BT, 4);
  const size_t preplane = (size_t)HWSZ * 4;  // shorts per [head][image] plane
  for (int g = 0; g < 2; g++) {
    const float* xg = x + (size_t)g * 4 * HWSZ;
    float* Sg = S + g * 64;
    float* outg = (float*)d_out + (size_t)g * 4 * HWSZ;
    k_conv1<<<gc1, blk, 0, stream>>>(xg, w1, b1, a1, t1);
    k_convm2<<<gconv, blk, 0, stream>>>(t1, wp2, b2, a2, t2);
    k_convm3<<<gconv3, dim3(512), 0, stream>>>(t2, wp3, b3, a3, t1);
    k_headm<<<gconv, blk, 0, stream>>>(t1, wph, hb[0], hb[1], hb[2], pre, Sg);
    k_blurcombine<<<gbc, blk, 0, stream>>>(xg, pre + 0 * 4 * preplane, Sg + 0, caa[0], cab[0], out1);
    k_blurcombine<<<gbc, blk, 0, stream>>>(out1, pre + 1 * 4 * preplane, Sg + 4, caa[1], cab[1], out2);
    k_blurcombine<<<gbc, blk, 0, stream>>>(out2, pre + 2 * 4 * preplane, Sg + 8, caa[2], cab[2], outg);
  }
}

// Round 14
// 523.250 us; speedup vs baseline: 1.4632x; 1.4632x over previous
//
#include <hip/hip_runtime.h>

#define HH 512
#define WW 512
#define NB 8
#define HWSZ (HH * WW)
#define PW 516   // padded row stride (cols 0..515; image at 1..512; col 513 zero; 514/515 junk)
#define PROWS 514  // rows 0..513; image rows at 1..512

typedef float f32x4 __attribute__((ext_vector_type(4)));
typedef float f32x16 __attribute__((ext_vector_type(16)));
typedef short bf16x8 __attribute__((ext_vector_type(8)));

__device__ __forceinline__ unsigned short f2bf(float f) {
  union { float f; unsigned u; } v; v.f = f;
  unsigned r = v.u + 0x7FFFu + ((v.u >> 16) & 1u);
  return (unsigned short)(r >> 16);
}
__device__ __forceinline__ float bf2f(unsigned u16) {
  union { unsigned u; float f; } v; v.u = u16 << 16;
  return v.f;
}

// async global->LDS copy, 16B per lane; dst wave-uniform base + lane*16
__device__ __forceinline__ void gload16(const uint4* g, uint4* l) {
  __builtin_amdgcn_global_load_lds((__attribute__((address_space(1))) void*)g,
                                   (__attribute__((address_space(3))) void*)l, 16, 0, 0);
}

// shorts per padded image plane (chunk-major: [row][chunk][col] 16B chunks)
#define PS1 ((size_t)PROWS * PW * 32)
#define PS2 ((size_t)PROWS * PW * 64)
#define NZ1 (2 * 4 * PW * 8 + 512 * 4 * 16)
#define NZ2 (2 * 8 * PW * 8 + 512 * 8 * 16)

__device__ __forceinline__ void zp(unsigned short* buf, int NCH, int i) {
  int rowShorts = NCH * PW * 8;
  if (i < 2 * rowShorts) {
    size_t r = (i < rowShorts) ? 0 : 513;
    int j = i % rowShorts;
    buf[r * rowShorts + j] = 0;
    return;
  }
  i -= 2 * rowShorts;
  int perRow = NCH * 16;
  int r = 1 + i / perRow;
  int j = i % perRow;
  int ch = j >> 4;
  int c = (j & 8) ? 513 : 0;
  int e = j & 7;
  buf[(((size_t)r * NCH + ch) * PW + c) * 8 + e] = 0;
}

// ---- fused one-time prep ----
// wp2 fragment order: [tap][ks][mt][lane][8]; wp3 fragment order: [tap][ks][lane][8].
__global__ __launch_bounds__(256) void k_prep(const float* __restrict__ w2,
                                              const float* __restrict__ w3,
                                              const float* __restrict__ h0,
                                              const float* __restrict__ h1,
                                              const float* __restrict__ h2,
                                              unsigned short* __restrict__ wp2,
                                              unsigned short* __restrict__ wp3,
                                              unsigned short* __restrict__ wph,
                                              unsigned short* __restrict__ t1,
                                              unsigned short* __restrict__ t2,
                                              float* __restrict__ S) {
  int i = blockIdx.x * 256 + threadIdx.x;
  const int N1 = 9 * 64 * 32;
  const int N2 = N1 + 9 * 32 * 64;
  const int N3 = N2 + 9 * 16 * 32;
  const int N4 = N3 + 4 * NZ1;
  const int N5 = N4 + 4 * NZ2;
  const int N6 = N5 + 128;
  if (i < N1) {  // conv2 weights, fragment order: j8|lane|mt|ks|tap
    int j8 = i & 7;
    int lane = (i >> 3) & 63;
    int mt = (i >> 9) & 1;
    int ks = (i >> 10) & 1;
    int tap = i >> 11;
    int l31 = lane & 31, h16 = lane >> 5;
    int oc = mt * 32 + l31;
    int ic = ks * 16 + h16 * 8 + j8;
    wp2[i] = f2bf(w2[(oc * 32 + ic) * 9 + tap]);
  } else if (i < N2) {  // conv3 weights, fragment order: j8|lane|ks|tap
    int j = i - N1;
    int j8 = j & 7;
    int lane = (j >> 3) & 63;
    int ks = (j >> 9) & 3;
    int tap = j >> 11;
    int l31 = lane & 31, h16 = lane >> 5;
    int ic = ks * 16 + h16 * 8 + j8;
    wp3[j] = f2bf(w3[(l31 * 64 + ic) * 9 + tap]);
  } else if (i < N3) {  // heads -> [9][16][32], oc 12..15 zero
    int j = i - N2;
    int ic = j & 31, t = j >> 5, oc = t & 15, k = t >> 4;
    float v = 0.f;
    if (oc < 12) {
      const float* w = oc < 4 ? h0 : (oc < 8 ? h1 : h2);
      v = w[((oc & 3) * 32 + ic) * 9 + k];
    }
    wph[j] = f2bf(v);
  } else if (i < N4) {
    int j = i - N3;
    zp(t1 + (size_t)(j / NZ1) * PS1, 4, j % NZ1);
  } else if (i < N5) {
    int j = i - N4;
    zp(t2 + (size_t)(j / NZ2) * PS2, 8, j % NZ2);
  } else if (i < N6) {
    S[i - N5] = 0.f;
  }
}

// ---- conv1: 1->32, VALU, fp32 in -> padded chunk-major bf16 out ----
__global__ __launch_bounds__(256) void k_conv1(const float* __restrict__ x,
                                               const float* __restrict__ w,
                                               const float* __restrict__ bias,
                                               const float* __restrict__ a_ptr,
                                               unsigned short* __restrict__ out) {
  const float* xp = x + (size_t)blockIdx.z * HWSZ;
  uint4* out4 = (uint4*)(out + (size_t)blockIdx.z * PS1);
  int pix = blockIdx.x * 256 + threadIdx.x;
  int h = pix >> 9, wc = pix & 511;
  float t[9];
#pragma unroll
  for (int dh = 0; dh < 3; dh++)
#pragma unroll
    for (int dw = 0; dw < 3; dw++) {
      int hh = h + dh - 1, ww = wc + dw - 1;
      t[dh * 3 + dw] =
          (hh >= 0 && hh < HH && ww >= 0 && ww < WW) ? xp[hh * WW + ww] : 0.f;
    }
  float a = a_ptr[0];
  unsigned pk[16];
#pragma unroll
  for (int oc = 0; oc < 32; oc++) {
    float s = bias[oc];
#pragma unroll
    for (int k = 0; k < 9; k++) s = fmaf(w[oc * 9 + k], t[k], s);
    s = s >= 0.f ? s : a * s;
    unsigned short b = f2bf(s);
    if (oc & 1)
      pk[oc >> 1] |= ((unsigned)b) << 16;
    else
      pk[oc >> 1] = b;
  }
#pragma unroll
  for (int q = 0; q < 4; q++)
    out4[((size_t)(h + 1) * 4 + q) * PW + (wc + 1)] = *(uint4*)&pk[q * 4];
}

// ---- conv2 (32->64): single-barrier 10-slot ring + fragment-order LDS weights ----
__global__ __launch_bounds__(256, 2) void k_convm2(const unsigned short* __restrict__ in,
                                                   const unsigned short* __restrict__ wp,
                                                   const float* __restrict__ bias,
                                                   const float* __restrict__ a_ptr,
                                                   unsigned short* __restrict__ out) {
  __shared__ __align__(16) short ring[10 * 4 * 68 * 8];  // 43520 B
  __shared__ __align__(16) short wlds[9 * 2 * 2 * 64 * 8];  // 36864 B, fragment order
  const int tid = threadIdx.x, lane = tid & 63, wid = tid >> 6;
  const int l31 = lane & 31, h16 = lane >> 5;
  const int c0 = blockIdx.x * 64;
  const int R0 = blockIdx.y * 32;
  const uint4* in4 = (const uint4*)(in + (size_t)blockIdx.z * PS1);
  unsigned short* outz = out + (size_t)blockIdx.z * PS2;
  uint4* ring4 = (uint4*)ring;
  uint4* wl4 = (uint4*)wlds;
  const uint4* wp4 = (const uint4*)wp;

  for (int sg = wid; sg < 36; sg += 4)
    gload16(wp4 + sg * 64 + lane, wl4 + sg * 64);

  auto load_rows = [&](int rfirst, int nrows) {
    int nseg = nrows * 4;
    for (int sg = wid; sg < nseg; sg += 4) {
      int rr = rfirst + (sg >> 2);
      int ch = sg & 3;
      const uint4* src = in4 + (size_t)(rr * 4 + ch) * PW + c0;
      uint4* dst = ring4 + ((rr % 10) * 4 + ch) * 68;
      gload16(src + lane, dst);
      gload16(src + 4 + lane, dst + 4);
    }
  };

  const float alpha = a_ptr[0];
  load_rows(R0, 6);

  for (int k = 0; k < 8; ++k) {
    const int rb = R0 + 4 * k;
    __syncthreads();
    if (k < 7) load_rows(rb + 6, 4);

    f32x16 acc[2][2];
#pragma unroll
    for (int nt = 0; nt < 2; nt++)
#pragma unroll
      for (int mt = 0; mt < 2; mt++)
#pragma unroll
        for (int j = 0; j < 16; j++) acc[nt][mt][j] = 0.f;

#pragma unroll
    for (int dh = 0; dh < 3; dh++) {
      bf16x8 af[3][2][2];
#pragma unroll
      for (int dw = 0; dw < 3; dw++)
#pragma unroll
        for (int ks = 0; ks < 2; ks++)
#pragma unroll
          for (int mt = 0; mt < 2; mt++)
            af[dw][ks][mt] = *(const bf16x8*)(
                wlds + ((((size_t)((dh * 3 + dw) * 2 + ks) * 2 + mt) * 64 + lane) * 8));
      const short* lrow = ring + (size_t)(((rb + wid + dh) % 10) * 4) * 68 * 8;
#pragma unroll
      for (int dw = 0; dw < 3; dw++) {
        const int pl0 = l31 + dw, pl1 = 32 + l31 + dw;
#pragma unroll
        for (int ks = 0; ks < 2; ks++) {
          const int blk = ks * 2 + h16;
          bf16x8 b0 = *(const bf16x8*)(lrow + (blk * 68 + pl0) * 8);
          bf16x8 b1 = *(const bf16x8*)(lrow + (blk * 68 + pl1) * 8);
#pragma unroll
          for (int mt = 0; mt < 2; mt++)
            acc[0][mt] = __builtin_amdgcn_mfma_f32_32x32x16_bf16(af[dw][ks][mt],
                                                                 b0, acc[0][mt], 0, 0, 0);
#pragma unroll
          for (int mt = 0; mt < 2; mt++)
            acc[1][mt] = __builtin_amdgcn_mfma_f32_32x32x16_bf16(af[dw][ks][mt],
                                                                 b1, acc[1][mt], 0, 0, 0);
        }
      }
    }

    const int orow = rb + wid + 1;
    uint2* o2 = (uint2*)outz;
#pragma unroll
    for (int nt = 0; nt < 2; nt++) {
      const int ocol = c0 + nt * 32 + l31 + 1;
#pragma unroll
      for (int mt = 0; mt < 2; mt++)
#pragma unroll
        for (int g = 0; g < 4; g++) {
          int oc0 = mt * 32 + g * 8 + h16 * 4;
          f32x4 bv = *(const f32x4*)(bias + oc0);
          float v[4];
#pragma unroll
          for (int j = 0; j < 4; j++) {
            float s = acc[nt][mt][g * 4 + j] + bv[j];
            v[j] = s >= 0.f ? s : alpha * s;
          }
          uint2 pk;
          pk.x = (unsigned)f2bf(v[0]) | ((unsigned)f2bf(v[1]) << 16);
          pk.y = (unsigned)f2bf(v[2]) | ((unsigned)f2bf(v[3]) << 16);
          size_t idx16 = ((size_t)orow * 8 + (mt * 4 + g)) * PW + ocol;
          o2[idx16 * 2 + h16] = pk;
        }
    }
  }
}

// ---- conv3 (64->32): split-IC 8-wave blocks, register weights, 8-slot ring ----
// Block: 512 thr = 4 row-waves x 2 ic-halves; 32 cols x 32 rows; partials summed via LDS.
// __launch_bounds__(512, 4): 4 waves/EU => 2 blocks/CU, 128-VGPR cap (72 wt + 16 acc fits).
__global__ __launch_bounds__(512, 4) void k_convm3(const unsigned short* __restrict__ in,
                                                   const unsigned short* __restrict__ wp,
                                                   const float* __restrict__ bias,
                                                   const float* __restrict__ a_ptr,
                                                   unsigned short* __restrict__ out) {
  __shared__ __align__(16) short ring[8 * 8 * 36 * 8];   // 36864 B
  __shared__ __align__(16) float red[4 * 4 * 64 * 4];    // 16384 B: [row][g][lane][4]
  const int tid = threadIdx.x, lane = tid & 63, wid = tid >> 6;
  const int l31 = lane & 31, h16 = lane >> 5;
  const int rw = wid & 3;      // row-wave
  const int ih = wid >> 2;     // ic half (0: ic 0..31, 1: ic 32..63)
  const int c0 = blockIdx.x * 32;
  const int R0 = blockIdx.y * 32;
  const uint4* in4 = (const uint4*)(in + (size_t)blockIdx.z * PS2);
  unsigned short* outz = out + (size_t)blockIdx.z * PS1;
  uint4* ring4 = (uint4*)ring;
  f32x4* red4 = (f32x4*)red;

  // register-resident weights for this ic half: 18 frags = 72 VGPR, no spill
  bf16x8 af[9][2];
#pragma unroll
  for (int t = 0; t < 9; t++)
#pragma unroll
    for (int kk = 0; kk < 2; kk++)
      af[t][kk] = *(const bf16x8*)(wp + ((size_t)(t * 4 + ih * 2 + kk) * 64 + lane) * 8);

  auto load_rows = [&](int rfirst, int nrows) {
    int nseg = nrows * 8;
    for (int sg = wid; sg < nseg; sg += 8) {
      int rr = rfirst + (sg >> 3);
      int ch = sg & 7;
      const uint4* src = in4 + (size_t)(rr * 8 + ch) * PW + c0;
      uint4* dst = ring4 + ((rr & 7) * 8 + ch) * 36;
      if (lane < 36) gload16(src + lane, dst);  // 36 px incl. +2 halo
    }
  };

  const float alpha = a_ptr[0];
  load_rows(R0, 6);

  for (int k = 0; k < 8; ++k) {
    const int rb = R0 + 4 * k;
    __syncthreads();                 // drains DMAs; prev iter's red reads done
    if (k < 7) load_rows(rb + 6, 2);

    f32x16 acc;
#pragma unroll
    for (int j = 0; j < 16; j++) acc[j] = 0.f;

#pragma unroll
    for (int dh = 0; dh < 3; dh++) {
      const short* lrow = ring + (size_t)(((rb + rw + dh) & 7) * 8) * 36 * 8;
#pragma unroll
      for (int dw = 0; dw < 3; dw++) {
        const int pl = l31 + dw;
#pragma unroll
        for (int kk = 0; kk < 2; kk++) {
          const int blk = (ih * 2 + kk) * 2 + h16;
          bf16x8 b = *(const bf16x8*)(lrow + (blk * 36 + pl) * 8);
          acc = __builtin_amdgcn_mfma_f32_32x32x16_bf16(af[dh * 3 + dw][kk], b, acc,
                                                        0, 0, 0);
        }
      }
    }

    // half-1 publishes partials (canonical 16B/lane layout, conflict-free)
    if (ih == 1) {
#pragma unroll
      for (int g = 0; g < 4; g++) {
        f32x4 v = {acc[g * 4 + 0], acc[g * 4 + 1], acc[g * 4 + 2], acc[g * 4 + 3]};
        red4[(rw * 4 + g) * 64 + lane] = v;
      }
    }
    __syncthreads();                 // red visible; slots rb,rb+1 free
    if (k < 7) load_rows(rb + 8, 2);

    if (ih == 0) {
      const int orow = rb + rw + 1;
      const int ocol = c0 + l31 + 1;
      uint2* o2 = (uint2*)outz;
#pragma unroll
      for (int g = 0; g < 4; g++) {
        f32x4 p = red4[(rw * 4 + g) * 64 + lane];
        int oc0 = g * 8 + h16 * 4;
        f32x4 bv = *(const f32x4*)(bias + oc0);
        float v[4];
#pragma unroll
        for (int j = 0; j < 4; j++) {
          float s = acc[g * 4 + j] + p[j] + bv[j];
          v[j] = s >= 0.f ? s : alpha * s;
        }
        uint2 pk;
        pk.x = (unsigned)f2bf(v[0]) | ((unsigned)f2bf(v[1]) << 16);
        pk.y = (unsigned)f2bf(v[2]) | ((unsigned)f2bf(v[3]) << 16);
        size_t idx16 = ((size_t)orow * 4 + g) * PW + ocol;
        o2[idx16 * 2 + h16] = pk;
      }
    }
  }
}

// ---- fused 3-head conv 32->16(12 real): strip-marching, gload16 staging ----
__global__ __launch_bounds__(256, 2) void k_headm(const unsigned short* __restrict__ in,
                                                  const unsigned short* __restrict__ wp,
                                                  const float* __restrict__ hb0,
                                                  const float* __restrict__ hb1,
                                                  const float* __restrict__ hb2,
                                                  unsigned short* __restrict__ pre,
                                                  float* __restrict__ S) {
  __shared__ __align__(16) short lds[8 * 4 * 68 * 8];  // 34816 B
  __shared__ float part[4][4][4];
  const int tid = threadIdx.x, lane = tid & 63, wid = tid >> 6;
  const int l15 = lane & 15, q = lane >> 4;
  const int c0 = blockIdx.x * 64;
  const int R0 = blockIdx.y * 32;
  const uint4* in4 = (const uint4*)(in + (size_t)blockIdx.z * PS1);
  float* Sz = S + blockIdx.z * 16;
  uint4* lds4 = (uint4*)lds;

  bf16x8 af[9];
#pragma unroll
  for (int k9 = 0; k9 < 9; k9++)
    af[k9] = *(const bf16x8*)(wp + (size_t)(k9 * 16 + l15) * 32 + q * 8);

  float bs[4];
#pragma unroll
  for (int r = 0; r < 4; r++) {
    int oc = q * 4 + r;
    bs[r] = oc < 4 ? hb0[oc] : (oc < 8 ? hb1[oc - 4] : (oc < 12 ? hb2[oc - 8] : 0.f));
  }
  unsigned short* prehq = pre + ((size_t)(q * 4 + blockIdx.z) * HWSZ) * 4;

  auto load_rows = [&](int rfirst, int nrows) {
    int nseg = nrows * 4;
    for (int sg = wid; sg < nseg; sg += 4) {
      int rr = rfirst + (sg >> 2);
      int ch = sg & 3;
      const uint4* src = in4 + (size_t)(rr * 4 + ch) * PW + c0;
      uint4* dst = lds4 + ((rr & 7) * 4 + ch) * 68;
      gload16(src + lane, dst);
      gload16(src + 4 + lane, dst + 4);
    }
  };

  load_rows(R0, 6);
  float csum[4] = {0.f, 0.f, 0.f, 0.f};

  for (int k = 0; k < 8; ++k) {
    const int rb = R0 + 4 * k;
    __syncthreads();
    if (k < 7) load_rows(rb + 6, 2);

    f32x4 acc[4];
#pragma unroll
    for (int nt = 0; nt < 4; nt++)
#pragma unroll
      for (int j = 0; j < 4; j++) acc[nt][j] = 0.f;

#pragma unroll
    for (int dh = 0; dh < 3; dh++) {
      const short* lrow = lds + (size_t)(((rb + wid + dh) & 7) * 4) * 68 * 8;
#pragma unroll
      for (int dw = 0; dw < 3; dw++) {
        bf16x8 a = af[dh * 3 + dw];
#pragma unroll
        for (int nt = 0; nt < 4; nt++) {
          int pl = nt * 16 + l15 + dw;
          bf16x8 b = *(const bf16x8*)(lrow + (q * 68 + pl) * 8);
          acc[nt] = __builtin_amdgcn_mfma_f32_16x16x32_bf16(a, b, acc[nt], 0, 0, 0);
        }
      }
    }

    const int orow = rb + wid;
#pragma unroll
    for (int nt = 0; nt < 4; nt++) {
      int pix = orow * 512 + c0 + nt * 16 + l15;
      float v[4];
#pragma unroll
      for (int r = 0; r < 4; r++) {
        v[r] = acc[nt][r] + bs[r];
        csum[r] += v[r];
      }
      uint2 pk;
      pk.x = (unsigned)f2bf(v[0]) | ((unsigned)f2bf(v[1]) << 16);
      pk.y = (unsigned)f2bf(v[2]) | ((unsigned)f2bf(v[3]) << 16);
      *(uint2*)(prehq + (size_t)pix * 4) = pk;
    }
    __syncthreads();
    if (k < 7) load_rows(rb + 8, 2);
  }

#pragma unroll
  for (int d = 1; d < 16; d <<= 1)
#pragma unroll
    for (int r = 0; r < 4; r++) csum[r] += __shfl_xor(csum[r], d, 64);
  if (l15 == 0)
#pragma unroll
    for (int r = 0; r < 4; r++) part[wid][q][r] = csum[r];
  __syncthreads();
  if (tid < 12) {
    int oc = tid;
    float s = part[0][oc >> 2][oc & 3] + part[1][oc >> 2][oc & 3] +
              part[2][oc >> 2][oc & 3] + part[3][oc >> 2][oc & 3];
    atomicAdd(&Sz[oc], s);
  }
}

// ---- fused: gate + 3 box blurs + softmax(gate*pre) + weighted combine ----
#define BT 32
#define RAD 12
#define SRCT (BT + 2 * RAD)  // 56
__global__ __launch_bounds__(256) void k_blurcombine(const float* __restrict__ src,
                                                     const unsigned short* __restrict__ preh,
                                                     const float* __restrict__ S4,
                                                     const float* __restrict__ wa,
                                                     const float* __restrict__ wb,
                                                     float* __restrict__ dst) {
  __shared__ float tile[SRCT][SRCT];
  __shared__ float hs[3][SRCT][BT];
  __shared__ float g[4];
  const float* srcz = src + (size_t)blockIdx.z * HWSZ;
  const unsigned short* prez = preh + (size_t)blockIdx.z * HWSZ * 4;
  const float* S4z = S4 + blockIdx.z * 16;
  float* dstz = dst + (size_t)blockIdx.z * HWSZ;
  int h0 = blockIdx.y * BT - RAD, w0 = blockIdx.x * BT - RAD;
  if (threadIdx.x < 4) {
    int o = threadIdx.x;
    float m[4], ga[4];
#pragma unroll
    for (int c = 0; c < 4; c++) m[c] = S4z[c] * (1.0f / (float)HWSZ);
#pragma unroll
    for (int c = 0; c < 4; c++) {
      float s = 0.f;
#pragma unroll
      for (int j = 0; j < 4; j++) s = fmaf(wa[c * 4 + j], m[j], s);
      ga[c] = fmaxf(s, 0.f);
    }
    float s2 = 0.f;
#pragma unroll
    for (int c = 0; c < 4; c++) s2 = fmaf(wb[o * 4 + c], ga[c], s2);
    g[o] = 1.f / (1.f + expf(-s2));
  }
  for (int idx = threadIdx.x; idx < SRCT * SRCT; idx += 256) {
    int r = idx / SRCT, c = idx % SRCT;
    int hh = h0 + r, ww = w0 + c;
    float v = 0.f;
    if (hh >= 0 && hh < HH && ww >= 0 && ww < WW) v = srcz[hh * WW + ww];
    tile[r][c] = v;
  }
  __syncthreads();
  for (int idx = threadIdx.x; idx < SRCT * BT; idx += 256) {
    int r = idx / BT, j = idx % BT;
    int cc = j + RAD;
    float s5 = 0.f;
#pragma unroll
    for (int d = -2; d <= 2; d++) s5 += tile[r][cc + d];
    float s15 = s5;
#pragma unroll
    for (int d = 3; d <= 7; d++) s15 += tile[r][cc + d] + tile[r][cc - d];
    float s25 = s15;
#pragma unroll
    for (int d = 8; d <= 12; d++) s25 += tile[r][cc + d] + tile[r][cc - d];
    hs[0][r][j] = s5;
    hs[1][r][j] = s15;
    hs[2][r][j] = s25;
  }
  __syncthreads();
  for (int p = threadIdx.x; p < BT * BT; p += 256) {
    int i = p / BT, j = p % BT;
    int rr = i + RAD;
    float b1 = 0.f;
#pragma unroll
    for (int d = -2; d <= 2; d++) b1 += hs[0][rr + d][j];
    float b2 = 0.f;
#pragma unroll
    for (int d = -7; d <= 7; d++) b2 += hs[1][rr + d][j];
    float b3 = 0.f;
#pragma unroll
    for (int d = -12; d <= 12; d++) b3 += hs[2][rr + d][j];
    b1 *= (1.f / 25.f);
    b2 *= (1.f / 225.f);
    b3 *= (1.f / 625.f);
    float b0 = tile[rr][j + RAD];
    int y = blockIdx.y * BT + i, x = blockIdx.x * BT + j;
    int pix = y * WW + x;
    uint2 pk = *(const uint2*)(prez + (size_t)pix * 4);
    float v[4];
    v[0] = bf2f(pk.x & 0xffffu) * g[0];
    v[1] = bf2f(pk.x >> 16) * g[1];
    v[2] = bf2f(pk.y & 0xffffu) * g[2];
    v[3] = bf2f(pk.y >> 16) * g[3];
    float mx = fmaxf(fmaxf(v[0], v[1]), fmaxf(v[2], v[3]));
    float e0 = expf(v[0] - mx), e1 = expf(v[1] - mx), e2 = expf(v[2] - mx),
          e3 = expf(v[3] - mx);
    float inv = 1.f / (e0 + e1 + e2 + e3);
    dstz[pix] = (e0 * b0 + e1 * b1 + e2 * b2 + e3 * b3) * inv;
  }
}

extern "C" void kernel_launch(void* const* d_in, const int* in_sizes, int n_in,
                              void* d_out, int out_size, void* d_ws, size_t ws_size,
                              hipStream_t stream) {
  const float* x = (const float*)d_in[0];
  const float* w1 = (const float*)d_in[1];
  const float* b1 = (const float*)d_in[2];
  const float* a1 = (const float*)d_in[3];
  const float* w2 = (const float*)d_in[4];
  const float* b2 = (const float*)d_in[5];
  const float* a2 = (const float*)d_in[6];
  const float* w3 = (const float*)d_in[7];
  const float* b3 = (const float*)d_in[8];
  const float* a3 = (const float*)d_in[9];
  const float* hw[3] = {(const float*)d_in[10], (const float*)d_in[14], (const float*)d_in[18]};
  const float* hb[3] = {(const float*)d_in[11], (const float*)d_in[15], (const float*)d_in[19]};
  const float* caa[3] = {(const float*)d_in[12], (const float*)d_in[16], (const float*)d_in[20]};
  const float* cab[3] = {(const float*)d_in[13], (const float*)d_in[17], (const float*)d_in[21]};

  char* base = (char*)d_ws;
  size_t off = 0;
  auto alloc = [&](size_t bytes) {
    char* p = base + off;
    off = (off + bytes + 63) & ~(size_t)63;
    return p;
  };
  unsigned short* t1 = (unsigned short*)alloc(4 * PS1 * 2);          // 67.9 MB
  unsigned short* t2 = (unsigned short*)alloc(4 * PS2 * 2);          // 135.8 MB
  unsigned short* pre = (unsigned short*)alloc(16 * (size_t)HWSZ * 4 * 2);  // 32 MB planar
  unsigned short* wp2 = (unsigned short*)alloc(9 * 64 * 32 * 2);
  unsigned short* wp3 = (unsigned short*)alloc(9 * 64 * 32 * 2);
  unsigned short* wph = (unsigned short*)alloc(9 * 16 * 32 * 2);
  float* out1 = (float*)alloc(4 * (size_t)HWSZ * 4);                 // 4 MB
  float* out2 = (float*)alloc(4 * (size_t)HWSZ * 4);                 // 4 MB
  float* S = (float*)alloc(8 * 16 * 4);

  dim3 blk(256);
  {
    int total = 9 * 64 * 32 + 9 * 32 * 64 + 9 * 16 * 32 + 4 * NZ1 + 4 * NZ2 + 128;
    k_prep<<<(total + 255) / 256, blk, 0, stream>>>(w2, w3, hw[0], hw[1], hw[2], wp2,
                                                    wp3, wph, t1, t2, S);
  }

  dim3 gc1(1024, 1, 4);
  dim3 gconv(8, 16, 4);     // 64-col strips x 32-row chunks x 4 images
  dim3 gconv3(16, 16, 4);   // 32-col strips x 32-row chunks x 4 images
  dim3 gbc(WW / BT, HH / BT, 4);
  const size_t preplane = (size_t)HWSZ * 4;  // shorts per [head][image] plane
  for (int g = 0; g < 2; g++) {
    const float* xg = x + (size_t)g * 4 * HWSZ;
    float* Sg = S + g * 64;
    float* outg = (float*)d_out + (size_t)g * 4 * HWSZ;
    k_conv1<<<gc1, blk, 0, stream>>>(xg, w1, b1, a1, t1);
    k_convm2<<<gconv, blk, 0, stream>>>(t1, wp2, b2, a2, t2);
    k_convm3<<<gconv3, dim3(512), 0, stream>>>(t2, wp3, b3, a3, t1);
    k_headm<<<gconv, blk, 0, stream>>>(t1, wph, hb[0], hb[1], hb[2], pre, Sg);
    k_blurcombine<<<gbc, blk, 0, stream>>>(xg, pre + 0 * 4 * preplane, Sg + 0, caa[0], cab[0], out1);
    k_blurcombine<<<gbc, blk, 0, stream>>>(out1, pre + 1 * 4 * preplane, Sg + 4, caa[1], cab[1], out2);
    k_blurcombine<<<gbc, blk, 0, stream>>>(out2, pre + 2 * 4 * preplane, Sg + 8, caa[2], cab[2], outg);
  }
}

// Round 15
// 482.432 us; speedup vs baseline: 1.5870x; 1.0846x over previous
//
#include <hip/hip_runtime.h>

#define HH 512
#define WW 512
#define NB 8
#define HWSZ (HH * WW)
#define PW 516   // padded row stride (cols 0..515; image at 1..512; col 513 zero; 514/515 junk)
#define PROWS 514  // rows 0..513; image rows at 1..512

typedef float f32x4 __attribute__((ext_vector_type(4)));
typedef float f32x16 __attribute__((ext_vector_type(16)));
typedef short bf16x8 __attribute__((ext_vector_type(8)));

__device__ __forceinline__ unsigned short f2bf(float f) {
  union { float f; unsigned u; } v; v.f = f;
  unsigned r = v.u + 0x7FFFu + ((v.u >> 16) & 1u);
  return (unsigned short)(r >> 16);
}
__device__ __forceinline__ float bf2f(unsigned u16) {
  union { unsigned u; float f; } v; v.u = u16 << 16;
  return v.f;
}

// async global->LDS copy, 16B per lane; dst wave-uniform base + lane*16
__device__ __forceinline__ void gload16(const uint4* g, uint4* l) {
  __builtin_amdgcn_global_load_lds((__attribute__((address_space(1))) void*)g,
                                   (__attribute__((address_space(3))) void*)l, 16, 0, 0);
}

// shorts per padded image plane (chunk-major: [row][chunk][col] 16B chunks)
#define PS1 ((size_t)PROWS * PW * 32)
#define PS2 ((size_t)PROWS * PW * 64)
#define NZ1 (2 * 4 * PW * 8 + 512 * 4 * 16)
#define NZ2 (2 * 8 * PW * 8 + 512 * 8 * 16)

__device__ __forceinline__ void zp(unsigned short* buf, int NCH, int i) {
  int rowShorts = NCH * PW * 8;
  if (i < 2 * rowShorts) {
    size_t r = (i < rowShorts) ? 0 : 513;
    int j = i % rowShorts;
    buf[r * rowShorts + j] = 0;
    return;
  }
  i -= 2 * rowShorts;
  int perRow = NCH * 16;
  int r = 1 + i / perRow;
  int j = i % perRow;
  int ch = j >> 4;
  int c = (j & 8) ? 513 : 0;
  int e = j & 7;
  buf[(((size_t)r * NCH + ch) * PW + c) * 8 + e] = 0;
}

// ---- fused one-time prep ----
// wp2 fragment order: [tap][ks][mt][lane][8]; wp3 fragment order: [tap][ks][lane][8].
__global__ __launch_bounds__(256) void k_prep(const float* __restrict__ w2,
                                              const float* __restrict__ w3,
                                              const float* __restrict__ h0,
                                              const float* __restrict__ h1,
                                              const float* __restrict__ h2,
                                              unsigned short* __restrict__ wp2,
                                              unsigned short* __restrict__ wp3,
                                              unsigned short* __restrict__ wph,
                                              unsigned short* __restrict__ t1,
                                              unsigned short* __restrict__ t2,
                                              float* __restrict__ S) {
  int i = blockIdx.x * 256 + threadIdx.x;
  const int N1 = 9 * 64 * 32;
  const int N2 = N1 + 9 * 32 * 64;
  const int N3 = N2 + 9 * 16 * 32;
  const int N4 = N3 + 4 * NZ1;
  const int N5 = N4 + 4 * NZ2;
  const int N6 = N5 + 128;
  if (i < N1) {  // conv2 weights, fragment order: j8|lane|mt|ks|tap
    int j8 = i & 7;
    int lane = (i >> 3) & 63;
    int mt = (i >> 9) & 1;
    int ks = (i >> 10) & 1;
    int tap = i >> 11;
    int l31 = lane & 31, h16 = lane >> 5;
    int oc = mt * 32 + l31;
    int ic = ks * 16 + h16 * 8 + j8;
    wp2[i] = f2bf(w2[(oc * 32 + ic) * 9 + tap]);
  } else if (i < N2) {  // conv3 weights, fragment order: j8|lane|ks|tap
    int j = i - N1;
    int j8 = j & 7;
    int lane = (j >> 3) & 63;
    int ks = (j >> 9) & 3;
    int tap = j >> 11;
    int l31 = lane & 31, h16 = lane >> 5;
    int ic = ks * 16 + h16 * 8 + j8;
    wp3[j] = f2bf(w3[(l31 * 64 + ic) * 9 + tap]);
  } else if (i < N3) {  // heads -> [9][16][32], oc 12..15 zero
    int j = i - N2;
    int ic = j & 31, t = j >> 5, oc = t & 15, k = t >> 4;
    float v = 0.f;
    if (oc < 12) {
      const float* w = oc < 4 ? h0 : (oc < 8 ? h1 : h2);
      v = w[((oc & 3) * 32 + ic) * 9 + k];
    }
    wph[j] = f2bf(v);
  } else if (i < N4) {
    int j = i - N3;
    zp(t1 + (size_t)(j / NZ1) * PS1, 4, j % NZ1);
  } else if (i < N5) {
    int j = i - N4;
    zp(t2 + (size_t)(j / NZ2) * PS2, 8, j % NZ2);
  } else if (i < N6) {
    S[i - N5] = 0.f;
  }
}

// ---- conv1: 1->32, VALU, fp32 in -> padded chunk-major bf16 out ----
__global__ __launch_bounds__(256) void k_conv1(const float* __restrict__ x,
                                               const float* __restrict__ w,
                                               const float* __restrict__ bias,
                                               const float* __restrict__ a_ptr,
                                               unsigned short* __restrict__ out) {
  const float* xp = x + (size_t)blockIdx.z * HWSZ;
  uint4* out4 = (uint4*)(out + (size_t)blockIdx.z * PS1);
  int pix = blockIdx.x * 256 + threadIdx.x;
  int h = pix >> 9, wc = pix & 511;
  float t[9];
#pragma unroll
  for (int dh = 0; dh < 3; dh++)
#pragma unroll
    for (int dw = 0; dw < 3; dw++) {
      int hh = h + dh - 1, ww = wc + dw - 1;
      t[dh * 3 + dw] =
          (hh >= 0 && hh < HH && ww >= 0 && ww < WW) ? xp[hh * WW + ww] : 0.f;
    }
  float a = a_ptr[0];
  unsigned pk[16];
#pragma unroll
  for (int oc = 0; oc < 32; oc++) {
    float s = bias[oc];
#pragma unroll
    for (int k = 0; k < 9; k++) s = fmaf(w[oc * 9 + k], t[k], s);
    s = s >= 0.f ? s : a * s;
    unsigned short b = f2bf(s);
    if (oc & 1)
      pk[oc >> 1] |= ((unsigned)b) << 16;
    else
      pk[oc >> 1] = b;
  }
#pragma unroll
  for (int q = 0; q < 4; q++)
    out4[((size_t)(h + 1) * 4 + q) * PW + (wc + 1)] = *(uint4*)&pk[q * 4];
}

// ---- conv2 (32->64): single-barrier 10-slot ring + fragment-order LDS weights ----
__global__ __launch_bounds__(256, 2) void k_convm2(const unsigned short* __restrict__ in,
                                                   const unsigned short* __restrict__ wp,
                                                   const float* __restrict__ bias,
                                                   const float* __restrict__ a_ptr,
                                                   unsigned short* __restrict__ out) {
  __shared__ __align__(16) short ring[10 * 4 * 68 * 8];  // 43520 B
  __shared__ __align__(16) short wlds[9 * 2 * 2 * 64 * 8];  // 36864 B, fragment order
  const int tid = threadIdx.x, lane = tid & 63, wid = tid >> 6;
  const int l31 = lane & 31, h16 = lane >> 5;
  const int c0 = blockIdx.x * 64;
  const int R0 = blockIdx.y * 32;
  const uint4* in4 = (const uint4*)(in + (size_t)blockIdx.z * PS1);
  unsigned short* outz = out + (size_t)blockIdx.z * PS2;
  uint4* ring4 = (uint4*)ring;
  uint4* wl4 = (uint4*)wlds;
  const uint4* wp4 = (const uint4*)wp;

  for (int sg = wid; sg < 36; sg += 4)
    gload16(wp4 + sg * 64 + lane, wl4 + sg * 64);

  auto load_rows = [&](int rfirst, int nrows) {
    int nseg = nrows * 4;
    for (int sg = wid; sg < nseg; sg += 4) {
      int rr = rfirst + (sg >> 2);
      int ch = sg & 3;
      const uint4* src = in4 + (size_t)(rr * 4 + ch) * PW + c0;
      uint4* dst = ring4 + ((rr % 10) * 4 + ch) * 68;
      gload16(src + lane, dst);
      gload16(src + 4 + lane, dst + 4);
    }
  };

  const float alpha = a_ptr[0];
  load_rows(R0, 6);

  for (int k = 0; k < 8; ++k) {
    const int rb = R0 + 4 * k;
    __syncthreads();
    if (k < 7) load_rows(rb + 6, 4);

    f32x16 acc[2][2];
#pragma unroll
    for (int nt = 0; nt < 2; nt++)
#pragma unroll
      for (int mt = 0; mt < 2; mt++)
#pragma unroll
        for (int j = 0; j < 16; j++) acc[nt][mt][j] = 0.f;

#pragma unroll
    for (int dh = 0; dh < 3; dh++) {
      bf16x8 af[3][2][2];
#pragma unroll
      for (int dw = 0; dw < 3; dw++)
#pragma unroll
        for (int ks = 0; ks < 2; ks++)
#pragma unroll
          for (int mt = 0; mt < 2; mt++)
            af[dw][ks][mt] = *(const bf16x8*)(
                wlds + ((((size_t)((dh * 3 + dw) * 2 + ks) * 2 + mt) * 64 + lane) * 8));
      const short* lrow = ring + (size_t)(((rb + wid + dh) % 10) * 4) * 68 * 8;
#pragma unroll
      for (int dw = 0; dw < 3; dw++) {
        const int pl0 = l31 + dw, pl1 = 32 + l31 + dw;
#pragma unroll
        for (int ks = 0; ks < 2; ks++) {
          const int blk = ks * 2 + h16;
          bf16x8 b0 = *(const bf16x8*)(lrow + (blk * 68 + pl0) * 8);
          bf16x8 b1 = *(const bf16x8*)(lrow + (blk * 68 + pl1) * 8);
#pragma unroll
          for (int mt = 0; mt < 2; mt++)
            acc[0][mt] = __builtin_amdgcn_mfma_f32_32x32x16_bf16(af[dw][ks][mt],
                                                                 b0, acc[0][mt], 0, 0, 0);
#pragma unroll
          for (int mt = 0; mt < 2; mt++)
            acc[1][mt] = __builtin_amdgcn_mfma_f32_32x32x16_bf16(af[dw][ks][mt],
                                                                 b1, acc[1][mt], 0, 0, 0);
        }
      }
    }

    const int orow = rb + wid + 1;
    uint2* o2 = (uint2*)outz;
#pragma unroll
    for (int nt = 0; nt < 2; nt++) {
      const int ocol = c0 + nt * 32 + l31 + 1;
#pragma unroll
      for (int mt = 0; mt < 2; mt++)
#pragma unroll
        for (int g = 0; g < 4; g++) {
          int oc0 = mt * 32 + g * 8 + h16 * 4;
          f32x4 bv = *(const f32x4*)(bias + oc0);
          float v[4];
#pragma unroll
          for (int j = 0; j < 4; j++) {
            float s = acc[nt][mt][g * 4 + j] + bv[j];
            v[j] = s >= 0.f ? s : alpha * s;
          }
          uint2 pk;
          pk.x = (unsigned)f2bf(v[0]) | ((unsigned)f2bf(v[1]) << 16);
          pk.y = (unsigned)f2bf(v[2]) | ((unsigned)f2bf(v[3]) << 16);
          size_t idx16 = ((size_t)orow * 8 + (mt * 4 + g)) * PW + ocol;
          o2[idx16 * 2 + h16] = pk;
        }
    }
  }
}

// ---- conv3 (64->32): 32-col blocks, 8-slot ring, REGISTER A-fragments ----
// A (36 frags = 144 VGPR) hoisted from LDS once per block. waves_per_eu(2,2)
// pins the allocator at 2 waves/EU (= the LDS-forced 2 blocks/CU) so the
// occupancy heuristic cannot shrink VGPRs below the array (R11/R14 lesson).
__global__ __attribute__((amdgpu_flat_work_group_size(256, 256),
                          amdgpu_waves_per_eu(2, 2)))
void k_convm3(const unsigned short* __restrict__ in,
              const unsigned short* __restrict__ wp,
              const float* __restrict__ bias,
              const float* __restrict__ a_ptr,
              unsigned short* __restrict__ out) {
  __shared__ __align__(16) short ring[8 * 8 * 36 * 8];   // 36864 B
  __shared__ __align__(16) short wlds[9 * 4 * 64 * 8];   // 36864 B, fragment order
  const int tid = threadIdx.x, lane = tid & 63, wid = tid >> 6;
  const int l31 = lane & 31, h16 = lane >> 5;
  const int c0 = blockIdx.x * 32;
  const int R0 = blockIdx.y * 32;
  const uint4* in4 = (const uint4*)(in + (size_t)blockIdx.z * PS2);
  unsigned short* outz = out + (size_t)blockIdx.z * PS1;
  uint4* ring4 = (uint4*)ring;
  uint4* wl4 = (uint4*)wlds;
  const uint4* wp4 = (const uint4*)wp;

  // weights once per block (36 segments of 1 KB)
  for (int sg = wid; sg < 36; sg += 4)
    gload16(wp4 + sg * 64 + lane, wl4 + sg * 64);

  auto load_rows = [&](int rfirst, int nrows) {
    int nseg = nrows * 8;
    for (int sg = wid; sg < nseg; sg += 4) {
      int rr = rfirst + (sg >> 3);
      int ch = sg & 7;
      const uint4* src = in4 + (size_t)(rr * 8 + ch) * PW + c0;
      uint4* dst = ring4 + ((rr & 7) * 8 + ch) * 36;
      if (lane < 36) gload16(src + lane, dst);  // 36 px incl. +2 halo
    }
  };

  const float alpha = a_ptr[0];
  load_rows(R0, 6);
  __syncthreads();  // weights + first rows resident

  // hoist all 36 A-fragments to registers (conflict-free base+lane*16 reads)
  bf16x8 af[9][4];
#pragma unroll
  for (int t = 0; t < 9; t++)
#pragma unroll
    for (int ks = 0; ks < 4; ks++)
      af[t][ks] = *(const bf16x8*)(wlds + (((size_t)(t * 4 + ks) * 64 + lane) * 8));

  for (int k = 0; k < 8; ++k) {
    const int rb = R0 + 4 * k;
    if (k) __syncthreads();          // drains row DMAs (k=0 drained above)
    if (k < 7) load_rows(rb + 6, 2);

    f32x16 acc;
#pragma unroll
    for (int j = 0; j < 16; j++) acc[j] = 0.f;

#pragma unroll
    for (int dh = 0; dh < 3; dh++) {
      const short* lrow = ring + (size_t)(((rb + wid + dh) & 7) * 8) * 36 * 8;
#pragma unroll
      for (int dw = 0; dw < 3; dw++) {
        const int pl = l31 + dw;
#pragma unroll
        for (int ks = 0; ks < 4; ks++) {
          const int blk = ks * 2 + h16;
          bf16x8 b = *(const bf16x8*)(lrow + (blk * 36 + pl) * 8);
          acc = __builtin_amdgcn_mfma_f32_32x32x16_bf16(af[dh * 3 + dw][ks], b, acc,
                                                        0, 0, 0);
        }
      }
    }

    const int orow = rb + wid + 1;
    const int ocol = c0 + l31 + 1;
    uint2* o2 = (uint2*)outz;
#pragma unroll
    for (int g = 0; g < 4; g++) {
      int oc0 = g * 8 + h16 * 4;
      f32x4 bv = *(const f32x4*)(bias + oc0);
      float v[4];
#pragma unroll
      for (int j = 0; j < 4; j++) {
        float s = acc[g * 4 + j] + bv[j];
        v[j] = s >= 0.f ? s : alpha * s;
      }
      uint2 pk;
      pk.x = (unsigned)f2bf(v[0]) | ((unsigned)f2bf(v[1]) << 16);
      pk.y = (unsigned)f2bf(v[2]) | ((unsigned)f2bf(v[3]) << 16);
      size_t idx16 = ((size_t)orow * 4 + g) * PW + ocol;
      o2[idx16 * 2 + h16] = pk;
    }
    __syncthreads();
    if (k < 7) load_rows(rb + 8, 2);
  }
}

// ---- fused 3-head conv 32->16(12 real): strip-marching, gload16 staging ----
__global__ __launch_bounds__(256, 2) void k_headm(const unsigned short* __restrict__ in,
                                                  const unsigned short* __restrict__ wp,
                                                  const float* __restrict__ hb0,
                                                  const float* __restrict__ hb1,
                                                  const float* __restrict__ hb2,
                                                  unsigned short* __restrict__ pre,
                                                  float* __restrict__ S) {
  __shared__ __align__(16) short lds[8 * 4 * 68 * 8];  // 34816 B
  __shared__ float part[4][4][4];
  const int tid = threadIdx.x, lane = tid & 63, wid = tid >> 6;
  const int l15 = lane & 15, q = lane >> 4;
  const int c0 = blockIdx.x * 64;
  const int R0 = blockIdx.y * 32;
  const uint4* in4 = (const uint4*)(in + (size_t)blockIdx.z * PS1);
  float* Sz = S + blockIdx.z * 16;
  uint4* lds4 = (uint4*)lds;

  bf16x8 af[9];
#pragma unroll
  for (int k9 = 0; k9 < 9; k9++)
    af[k9] = *(const bf16x8*)(wp + (size_t)(k9 * 16 + l15) * 32 + q * 8);

  float bs[4];
#pragma unroll
  for (int r = 0; r < 4; r++) {
    int oc = q * 4 + r;
    bs[r] = oc < 4 ? hb0[oc] : (oc < 8 ? hb1[oc - 4] : (oc < 12 ? hb2[oc - 8] : 0.f));
  }
  unsigned short* prehq = pre + ((size_t)(q * 4 + blockIdx.z) * HWSZ) * 4;

  auto load_rows = [&](int rfirst, int nrows) {
    int nseg = nrows * 4;
    for (int sg = wid; sg < nseg; sg += 4) {
      int rr = rfirst + (sg >> 2);
      int ch = sg & 3;
      const uint4* src = in4 + (size_t)(rr * 4 + ch) * PW + c0;
      uint4* dst = lds4 + ((rr & 7) * 4 + ch) * 68;
      gload16(src + lane, dst);
      gload16(src + 4 + lane, dst + 4);
    }
  };

  load_rows(R0, 6);
  float csum[4] = {0.f, 0.f, 0.f, 0.f};

  for (int k = 0; k < 8; ++k) {
    const int rb = R0 + 4 * k;
    __syncthreads();
    if (k < 7) load_rows(rb + 6, 2);

    f32x4 acc[4];
#pragma unroll
    for (int nt = 0; nt < 4; nt++)
#pragma unroll
      for (int j = 0; j < 4; j++) acc[nt][j] = 0.f;

#pragma unroll
    for (int dh = 0; dh < 3; dh++) {
      const short* lrow = lds + (size_t)(((rb + wid + dh) & 7) * 4) * 68 * 8;
#pragma unroll
      for (int dw = 0; dw < 3; dw++) {
        bf16x8 a = af[dh * 3 + dw];
#pragma unroll
        for (int nt = 0; nt < 4; nt++) {
          int pl = nt * 16 + l15 + dw;
          bf16x8 b = *(const bf16x8*)(lrow + (q * 68 + pl) * 8);
          acc[nt] = __builtin_amdgcn_mfma_f32_16x16x32_bf16(a, b, acc[nt], 0, 0, 0);
        }
      }
    }

    const int orow = rb + wid;
#pragma unroll
    for (int nt = 0; nt < 4; nt++) {
      int pix = orow * 512 + c0 + nt * 16 + l15;
      float v[4];
#pragma unroll
      for (int r = 0; r < 4; r++) {
        v[r] = acc[nt][r] + bs[r];
        csum[r] += v[r];
      }
      uint2 pk;
      pk.x = (unsigned)f2bf(v[0]) | ((unsigned)f2bf(v[1]) << 16);
      pk.y = (unsigned)f2bf(v[2]) | ((unsigned)f2bf(v[3]) << 16);
      *(uint2*)(prehq + (size_t)pix * 4) = pk;
    }
    __syncthreads();
    if (k < 7) load_rows(rb + 8, 2);
  }

#pragma unroll
  for (int d = 1; d < 16; d <<= 1)
#pragma unroll
    for (int r = 0; r < 4; r++) csum[r] += __shfl_xor(csum[r], d, 64);
  if (l15 == 0)
#pragma unroll
    for (int r = 0; r < 4; r++) part[wid][q][r] = csum[r];
  __syncthreads();
  if (tid < 12) {
    int oc = tid;
    float s = part[0][oc >> 2][oc & 3] + part[1][oc >> 2][oc & 3] +
              part[2][oc >> 2][oc & 3] + part[3][oc >> 2][oc & 3];
    atomicAdd(&Sz[oc], s);
  }
}

// ---- fused: gate + 3 box blurs + softmax(gate*pre) + weighted combine ----
#define BT 32
#define RAD 12
#define SRCT (BT + 2 * RAD)  // 56
__global__ __launch_bounds__(256) void k_blurcombine(const float* __restrict__ src,
                                                     const unsigned short* __restrict__ preh,
                                                     const float* __restrict__ S4,
                                                     const float* __restrict__ wa,
                                                     const float* __restrict__ wb,
                                                     float* __restrict__ dst) {
  __shared__ float tile[SRCT][SRCT];
  __shared__ float hs[3][SRCT][BT];
  __shared__ float g[4];
  const float* srcz = src + (size_t)blockIdx.z * HWSZ;
  const unsigned short* prez = preh + (size_t)blockIdx.z * HWSZ * 4;
  const float* S4z = S4 + blockIdx.z * 16;
  float* dstz = dst + (size_t)blockIdx.z * HWSZ;
  int h0 = blockIdx.y * BT - RAD, w0 = blockIdx.x * BT - RAD;
  if (threadIdx.x < 4) {
    int o = threadIdx.x;
    float m[4], ga[4];
#pragma unroll
    for (int c = 0; c < 4; c++) m[c] = S4z[c] * (1.0f / (float)HWSZ);
#pragma unroll
    for (int c = 0; c < 4; c++) {
      float s = 0.f;
#pragma unroll
      for (int j = 0; j < 4; j++) s = fmaf(wa[c * 4 + j], m[j], s);
      ga[c] = fmaxf(s, 0.f);
    }
    float s2 = 0.f;
#pragma unroll
    for (int c = 0; c < 4; c++) s2 = fmaf(wb[o * 4 + c], ga[c], s2);
    g[o] = 1.f / (1.f + expf(-s2));
  }
  for (int idx = threadIdx.x; idx < SRCT * SRCT; idx += 256) {
    int r = idx / SRCT, c = idx % SRCT;
    int hh = h0 + r, ww = w0 + c;
    float v = 0.f;
    if (hh >= 0 && hh < HH && ww >= 0 && ww < WW) v = srcz[hh * WW + ww];
    tile[r][c] = v;
  }
  __syncthreads();
  for (int idx = threadIdx.x; idx < SRCT * BT; idx += 256) {
    int r = idx / BT, j = idx % BT;
    int cc = j + RAD;
    float s5 = 0.f;
#pragma unroll
    for (int d = -2; d <= 2; d++) s5 += tile[r][cc + d];
    float s15 = s5;
#pragma unroll
    for (int d = 3; d <= 7; d++) s15 += tile[r][cc + d] + tile[r][cc - d];
    float s25 = s15;
#pragma unroll
    for (int d = 8; d <= 12; d++) s25 += tile[r][cc + d] + tile[r][cc - d];
    hs[0][r][j] = s5;
    hs[1][r][j] = s15;
    hs[2][r][j] = s25;
  }
  __syncthreads();
  for (int p = threadIdx.x; p < BT * BT; p += 256) {
    int i = p / BT, j = p % BT;
    int rr = i + RAD;
    float b1 = 0.f;
#pragma unroll
    for (int d = -2; d <= 2; d++) b1 += hs[0][rr + d][j];
    float b2 = 0.f;
#pragma unroll
    for (int d = -7; d <= 7; d++) b2 += hs[1][rr + d][j];
    float b3 = 0.f;
#pragma unroll
    for (int d = -12; d <= 12; d++) b3 += hs[2][rr + d][j];
    b1 *= (1.f / 25.f);
    b2 *= (1.f / 225.f);
    b3 *= (1.f / 625.f);
    float b0 = tile[rr][j + RAD];
    int y = blockIdx.y * BT + i, x = blockIdx.x * BT + j;
    int pix = y * WW + x;
    uint2 pk = *(const uint2*)(prez + (size_t)pix * 4);
    float v[4];
    v[0] = bf2f(pk.x & 0xffffu) * g[0];
    v[1] = bf2f(pk.x >> 16) * g[1];
    v[2] = bf2f(pk.y & 0xffffu) * g[2];
    v[3] = bf2f(pk.y >> 16) * g[3];
    float mx = fmaxf(fmaxf(v[0], v[1]), fmaxf(v[2], v[3]));
    float e0 = expf(v[0] - mx), e1 = expf(v[1] - mx), e2 = expf(v[2] - mx),
          e3 = expf(v[3] - mx);
    float inv = 1.f / (e0 + e1 + e2 + e3);
    dstz[pix] = (e0 * b0 + e1 * b1 + e2 * b2 + e3 * b3) * inv;
  }
}

extern "C" void kernel_launch(void* const* d_in, const int* in_sizes, int n_in,
                              void* d_out, int out_size, void* d_ws, size_t ws_size,
                              hipStream_t stream) {
  const float* x = (const float*)d_in[0];
  const float* w1 = (const float*)d_in[1];
  const float* b1 = (const float*)d_in[2];
  const float* a1 = (const float*)d_in[3];
  const float* w2 = (const float*)d_in[4];
  const float* b2 = (const float*)d_in[5];
  const float* a2 = (const float*)d_in[6];
  const float* w3 = (const float*)d_in[7];
  const float* b3 = (const float*)d_in[8];
  const float* a3 = (const float*)d_in[9];
  const float* hw[3] = {(const float*)d_in[10], (const float*)d_in[14], (const float*)d_in[18]};
  const float* hb[3] = {(const float*)d_in[11], (const float*)d_in[15], (const float*)d_in[19]};
  const float* caa[3] = {(const float*)d_in[12], (const float*)d_in[16], (const float*)d_in[20]};
  const float* cab[3] = {(const float*)d_in[13], (const float*)d_in[17], (const float*)d_in[21]};

  char* base = (char*)d_ws;
  size_t off = 0;
  auto alloc = [&](size_t bytes) {
    char* p = base + off;
    off = (off + bytes + 63) & ~(size_t)63;
    return p;
  };
  unsigned short* t1 = (unsigned short*)alloc(4 * PS1 * 2);          // 67.9 MB
  unsigned short* t2 = (unsigned short*)alloc(4 * PS2 * 2);          // 135.8 MB
  unsigned short* pre = (unsigned short*)alloc(16 * (size_t)HWSZ * 4 * 2);  // 32 MB planar
  unsigned short* wp2 = (unsigned short*)alloc(9 * 64 * 32 * 2);
  unsigned short* wp3 = (unsigned short*)alloc(9 * 64 * 32 * 2);
  unsigned short* wph = (unsigned short*)alloc(9 * 16 * 32 * 2);
  float* out1 = (float*)alloc(4 * (size_t)HWSZ * 4);                 // 4 MB
  float* out2 = (float*)alloc(4 * (size_t)HWSZ * 4);                 // 4 MB
  float* S = (float*)alloc(8 * 16 * 4);

  dim3 blk(256);
  {
    int total = 9 * 64 * 32 + 9 * 32 * 64 + 9 * 16 * 32 + 4 * NZ1 + 4 * NZ2 + 128;
    k_prep<<<(total + 255) / 256, blk, 0, stream>>>(w2, w3, hw[0], hw[1], hw[2], wp2,
                                                    wp3, wph, t1, t2, S);
  }

  dim3 gc1(1024, 1, 4);
  dim3 gconv(8, 16, 4);     // 64-col strips x 32-row chunks x 4 images
  dim3 gconv3(16, 16, 4);   // 32-col strips x 32-row chunks x 4 images
  dim3 gbc(WW / BT, HH / BT, 4);
  const size_t preplane = (size_t)HWSZ * 4;  // shorts per [head][image] plane
  for (int g = 0; g < 2; g++) {
    const float* xg = x + (size_t)g * 4 * HWSZ;
    float* Sg = S + g * 64;
    float* outg = (float*)d_out + (size_t)g * 4 * HWSZ;
    k_conv1<<<gc1, blk, 0, stream>>>(xg, w1, b1, a1, t1);
    k_convm2<<<gconv, blk, 0, stream>>>(t1, wp2, b2, a2, t2);
    k_convm3<<<gconv3, blk, 0, stream>>>(t2, wp3, b3, a3, t1);
    k_headm<<<gconv, blk, 0, stream>>>(t1, wph, hb[0], hb[1], hb[2], pre, Sg);
    k_blurcombine<<<gbc, blk, 0, stream>>>(xg, pre + 0 * 4 * preplane, Sg + 0, caa[0], cab[0], out1);
    k_blurcombine<<<gbc, blk, 0, stream>>>(out1, pre + 1 * 4 * preplane, Sg + 4, caa[1], cab[1], out2);
    k_blurcombine<<<gbc, blk, 0, stream>>>(out2, pre + 2 * 4 * preplane, Sg + 8, caa[2], cab[2], outg);
  }
}

// Round 16
// 451.562 us; speedup vs baseline: 1.6955x; 1.0684x over previous
//
#include <hip/hip_runtime.h>

#define HH 512
#define WW 512
#define NB 8
#define HWSZ (HH * WW)
#define PW 516   // padded row stride (cols 0..515; image at 1..512; col 513 zero; 514/515 junk)
#define PROWS 514  // rows 0..513; image rows at 1..512

typedef float f32x4 __attribute__((ext_vector_type(4)));
typedef float f32x16 __attribute__((ext_vector_type(16)));
typedef short bf16x8 __attribute__((ext_vector_type(8)));

__device__ __forceinline__ unsigned short f2bf(float f) {
  union { float f; unsigned u; } v; v.f = f;
  unsigned r = v.u + 0x7FFFu + ((v.u >> 16) & 1u);
  return (unsigned short)(r >> 16);
}
__device__ __forceinline__ float bf2f(unsigned u16) {
  union { unsigned u; float f; } v; v.u = u16 << 16;
  return v.f;
}

// async global->LDS copy, 16B per lane; dst wave-uniform base + lane*16
__device__ __forceinline__ void gload16(const uint4* g, uint4* l) {
  __builtin_amdgcn_global_load_lds((__attribute__((address_space(1))) void*)g,
                                   (__attribute__((address_space(3))) void*)l, 16, 0, 0);
}

// shorts per padded image plane (chunk-major: [row][chunk][col] 16B chunks)
#define PS1 ((size_t)PROWS * PW * 32)
#define PS2 ((size_t)PROWS * PW * 64)
#define NZ1 (2 * 4 * PW * 8 + 512 * 4 * 16)
#define NZ2 (2 * 8 * PW * 8 + 512 * 8 * 16)

__device__ __forceinline__ void zp(unsigned short* buf, int NCH, int i) {
  int rowShorts = NCH * PW * 8;
  if (i < 2 * rowShorts) {
    size_t r = (i < rowShorts) ? 0 : 513;
    int j = i % rowShorts;
    buf[r * rowShorts + j] = 0;
    return;
  }
  i -= 2 * rowShorts;
  int perRow = NCH * 16;
  int r = 1 + i / perRow;
  int j = i % perRow;
  int ch = j >> 4;
  int c = (j & 8) ? 513 : 0;
  int e = j & 7;
  buf[(((size_t)r * NCH + ch) * PW + c) * 8 + e] = 0;
}

// ---- fused one-time prep ----
// wp2 fragment order: [tap][ks][mt][lane][8]; wp3 fragment order: [tap][ks][lane][8].
__global__ __launch_bounds__(256) void k_prep(const float* __restrict__ w2,
                                              const float* __restrict__ w3,
                                              const float* __restrict__ h0,
                                              const float* __restrict__ h1,
                                              const float* __restrict__ h2,
                                              unsigned short* __restrict__ wp2,
                                              unsigned short* __restrict__ wp3,
                                              unsigned short* __restrict__ wph,
                                              unsigned short* __restrict__ t1,
                                              unsigned short* __restrict__ t2,
                                              float* __restrict__ S) {
  int i = blockIdx.x * 256 + threadIdx.x;
  const int N1 = 9 * 64 * 32;
  const int N2 = N1 + 9 * 32 * 64;
  const int N3 = N2 + 9 * 16 * 32;
  const int N4 = N3 + 4 * NZ1;
  const int N5 = N4 + 4 * NZ2;
  const int N6 = N5 + 128;
  if (i < N1) {  // conv2 weights, fragment order: j8|lane|mt|ks|tap
    int j8 = i & 7;
    int lane = (i >> 3) & 63;
    int mt = (i >> 9) & 1;
    int ks = (i >> 10) & 1;
    int tap = i >> 11;
    int l31 = lane & 31, h16 = lane >> 5;
    int oc = mt * 32 + l31;
    int ic = ks * 16 + h16 * 8 + j8;
    wp2[i] = f2bf(w2[(oc * 32 + ic) * 9 + tap]);
  } else if (i < N2) {  // conv3 weights, fragment order: j8|lane|ks|tap
    int j = i - N1;
    int j8 = j & 7;
    int lane = (j >> 3) & 63;
    int ks = (j >> 9) & 3;
    int tap = j >> 11;
    int l31 = lane & 31, h16 = lane >> 5;
    int ic = ks * 16 + h16 * 8 + j8;
    wp3[j] = f2bf(w3[(l31 * 64 + ic) * 9 + tap]);
  } else if (i < N3) {  // heads -> [9][16][32], oc 12..15 zero
    int j = i - N2;
    int ic = j & 31, t = j >> 5, oc = t & 15, k = t >> 4;
    float v = 0.f;
    if (oc < 12) {
      const float* w = oc < 4 ? h0 : (oc < 8 ? h1 : h2);
      v = w[((oc & 3) * 32 + ic) * 9 + k];
    }
    wph[j] = f2bf(v);
  } else if (i < N4) {
    int j = i - N3;
    zp(t1 + (size_t)(j / NZ1) * PS1, 4, j % NZ1);
  } else if (i < N5) {
    int j = i - N4;
    zp(t2 + (size_t)(j / NZ2) * PS2, 8, j % NZ2);
  } else if (i < N6) {
    S[i - N5] = 0.f;
  }
}

// ---- conv1: 1->32, VALU, fp32 in -> padded chunk-major bf16 out ----
__global__ __launch_bounds__(256) void k_conv1(const float* __restrict__ x,
                                               const float* __restrict__ w,
                                               const float* __restrict__ bias,
                                               const float* __restrict__ a_ptr,
                                               unsigned short* __restrict__ out) {
  const float* xp = x + (size_t)blockIdx.z * HWSZ;
  uint4* out4 = (uint4*)(out + (size_t)blockIdx.z * PS1);
  int pix = blockIdx.x * 256 + threadIdx.x;
  int h = pix >> 9, wc = pix & 511;
  float t[9];
#pragma unroll
  for (int dh = 0; dh < 3; dh++)
#pragma unroll
    for (int dw = 0; dw < 3; dw++) {
      int hh = h + dh - 1, ww = wc + dw - 1;
      t[dh * 3 + dw] =
          (hh >= 0 && hh < HH && ww >= 0 && ww < WW) ? xp[hh * WW + ww] : 0.f;
    }
  float a = a_ptr[0];
  unsigned pk[16];
#pragma unroll
  for (int oc = 0; oc < 32; oc++) {
    float s = bias[oc];
#pragma unroll
    for (int k = 0; k < 9; k++) s = fmaf(w[oc * 9 + k], t[k], s);
    s = s >= 0.f ? s : a * s;
    unsigned short b = f2bf(s);
    if (oc & 1)
      pk[oc >> 1] |= ((unsigned)b) << 16;
    else
      pk[oc >> 1] = b;
  }
#pragma unroll
  for (int q = 0; q < 4; q++)
    out4[((size_t)(h + 1) * 4 + q) * PW + (wc + 1)] = *(uint4*)&pk[q * 4];
}

// ---- conv2 (32->64): single-barrier 10-slot ring + fragment-order LDS weights ----
__global__ __launch_bounds__(256, 2) void k_convm2(const unsigned short* __restrict__ in,
                                                   const unsigned short* __restrict__ wp,
                                                   const float* __restrict__ bias,
                                                   const float* __restrict__ a_ptr,
                                                   unsigned short* __restrict__ out) {
  __shared__ __align__(16) short ring[10 * 4 * 68 * 8];  // 43520 B
  __shared__ __align__(16) short wlds[9 * 2 * 2 * 64 * 8];  // 36864 B, fragment order
  const int tid = threadIdx.x, lane = tid & 63, wid = tid >> 6;
  const int l31 = lane & 31, h16 = lane >> 5;
  const int c0 = blockIdx.x * 64;
  const int R0 = blockIdx.y * 32;
  const uint4* in4 = (const uint4*)(in + (size_t)blockIdx.z * PS1);
  unsigned short* outz = out + (size_t)blockIdx.z * PS2;
  uint4* ring4 = (uint4*)ring;
  uint4* wl4 = (uint4*)wlds;
  const uint4* wp4 = (const uint4*)wp;

  for (int sg = wid; sg < 36; sg += 4)
    gload16(wp4 + sg * 64 + lane, wl4 + sg * 64);

  auto load_rows = [&](int rfirst, int nrows) {
    int nseg = nrows * 4;
    for (int sg = wid; sg < nseg; sg += 4) {
      int rr = rfirst + (sg >> 2);
      int ch = sg & 3;
      const uint4* src = in4 + (size_t)(rr * 4 + ch) * PW + c0;
      uint4* dst = ring4 + ((rr % 10) * 4 + ch) * 68;
      gload16(src + lane, dst);
      gload16(src + 4 + lane, dst + 4);
    }
  };

  const float alpha = a_ptr[0];
  load_rows(R0, 6);

  for (int k = 0; k < 8; ++k) {
    const int rb = R0 + 4 * k;
    __syncthreads();
    if (k < 7) load_rows(rb + 6, 4);

    f32x16 acc[2][2];
#pragma unroll
    for (int nt = 0; nt < 2; nt++)
#pragma unroll
      for (int mt = 0; mt < 2; mt++)
#pragma unroll
        for (int j = 0; j < 16; j++) acc[nt][mt][j] = 0.f;

#pragma unroll
    for (int dh = 0; dh < 3; dh++) {
      bf16x8 af[3][2][2];
#pragma unroll
      for (int dw = 0; dw < 3; dw++)
#pragma unroll
        for (int ks = 0; ks < 2; ks++)
#pragma unroll
          for (int mt = 0; mt < 2; mt++)
            af[dw][ks][mt] = *(const bf16x8*)(
                wlds + ((((size_t)((dh * 3 + dw) * 2 + ks) * 2 + mt) * 64 + lane) * 8));
      const short* lrow = ring + (size_t)(((rb + wid + dh) % 10) * 4) * 68 * 8;
#pragma unroll
      for (int dw = 0; dw < 3; dw++) {
        const int pl0 = l31 + dw, pl1 = 32 + l31 + dw;
#pragma unroll
        for (int ks = 0; ks < 2; ks++) {
          const int blk = ks * 2 + h16;
          bf16x8 b0 = *(const bf16x8*)(lrow + (blk * 68 + pl0) * 8);
          bf16x8 b1 = *(const bf16x8*)(lrow + (blk * 68 + pl1) * 8);
#pragma unroll
          for (int mt = 0; mt < 2; mt++)
            acc[0][mt] = __builtin_amdgcn_mfma_f32_32x32x16_bf16(af[dw][ks][mt],
                                                                 b0, acc[0][mt], 0, 0, 0);
#pragma unroll
          for (int mt = 0; mt < 2; mt++)
            acc[1][mt] = __builtin_amdgcn_mfma_f32_32x32x16_bf16(af[dw][ks][mt],
                                                                 b1, acc[1][mt], 0, 0, 0);
        }
      }
    }

    const int orow = rb + wid + 1;
    uint2* o2 = (uint2*)outz;
#pragma unroll
    for (int nt = 0; nt < 2; nt++) {
      const int ocol = c0 + nt * 32 + l31 + 1;
#pragma unroll
      for (int mt = 0; mt < 2; mt++)
#pragma unroll
        for (int g = 0; g < 4; g++) {
          int oc0 = mt * 32 + g * 8 + h16 * 4;
          f32x4 bv = *(const f32x4*)(bias + oc0);
          float v[4];
#pragma unroll
          for (int j = 0; j < 4; j++) {
            float s = acc[nt][mt][g * 4 + j] + bv[j];
            v[j] = s >= 0.f ? s : alpha * s;
          }
          uint2 pk;
          pk.x = (unsigned)f2bf(v[0]) | ((unsigned)f2bf(v[1]) << 16);
          pk.y = (unsigned)f2bf(v[2]) | ((unsigned)f2bf(v[3]) << 16);
          size_t idx16 = ((size_t)orow * 8 + (mt * 4 + g)) * PW + ocol;
          o2[idx16 * 2 + h16] = pk;
        }
    }
  }
}

// ---- conv3 (64->32): 32-col blocks, 8-slot ring, register-hoisted A-fragments ----
__global__ __attribute__((amdgpu_flat_work_group_size(256, 256),
                          amdgpu_waves_per_eu(2, 2)))
void k_convm3(const unsigned short* __restrict__ in,
              const unsigned short* __restrict__ wp,
              const float* __restrict__ bias,
              const float* __restrict__ a_ptr,
              unsigned short* __restrict__ out) {
  __shared__ __align__(16) short ring[8 * 8 * 36 * 8];   // 36864 B
  __shared__ __align__(16) short wlds[9 * 4 * 64 * 8];   // 36864 B, fragment order
  const int tid = threadIdx.x, lane = tid & 63, wid = tid >> 6;
  const int l31 = lane & 31, h16 = lane >> 5;
  const int c0 = blockIdx.x * 32;
  const int R0 = blockIdx.y * 32;
  const uint4* in4 = (const uint4*)(in + (size_t)blockIdx.z * PS2);
  unsigned short* outz = out + (size_t)blockIdx.z * PS1;
  uint4* ring4 = (uint4*)ring;
  uint4* wl4 = (uint4*)wlds;
  const uint4* wp4 = (const uint4*)wp;

  for (int sg = wid; sg < 36; sg += 4)
    gload16(wp4 + sg * 64 + lane, wl4 + sg * 64);

  auto load_rows = [&](int rfirst, int nrows) {
    int nseg = nrows * 8;
    for (int sg = wid; sg < nseg; sg += 4) {
      int rr = rfirst + (sg >> 3);
      int ch = sg & 7;
      const uint4* src = in4 + (size_t)(rr * 8 + ch) * PW + c0;
      uint4* dst = ring4 + ((rr & 7) * 8 + ch) * 36;
      if (lane < 36) gload16(src + lane, dst);  // 36 px incl. +2 halo
    }
  };

  const float alpha = a_ptr[0];
  load_rows(R0, 6);
  __syncthreads();  // weights + first rows resident

  bf16x8 af[9][4];
#pragma unroll
  for (int t = 0; t < 9; t++)
#pragma unroll
    for (int ks = 0; ks < 4; ks++)
      af[t][ks] = *(const bf16x8*)(wlds + (((size_t)(t * 4 + ks) * 64 + lane) * 8));

  for (int k = 0; k < 8; ++k) {
    const int rb = R0 + 4 * k;
    if (k) __syncthreads();
    if (k < 7) load_rows(rb + 6, 2);

    f32x16 acc;
#pragma unroll
    for (int j = 0; j < 16; j++) acc[j] = 0.f;

#pragma unroll
    for (int dh = 0; dh < 3; dh++) {
      const short* lrow = ring + (size_t)(((rb + wid + dh) & 7) * 8) * 36 * 8;
#pragma unroll
      for (int dw = 0; dw < 3; dw++) {
        const int pl = l31 + dw;
#pragma unroll
        for (int ks = 0; ks < 4; ks++) {
          const int blk = ks * 2 + h16;
          bf16x8 b = *(const bf16x8*)(lrow + (blk * 36 + pl) * 8);
          acc = __builtin_amdgcn_mfma_f32_32x32x16_bf16(af[dh * 3 + dw][ks], b, acc,
                                                        0, 0, 0);
        }
      }
    }

    const int orow = rb + wid + 1;
    const int ocol = c0 + l31 + 1;
    uint2* o2 = (uint2*)outz;
#pragma unroll
    for (int g = 0; g < 4; g++) {
      int oc0 = g * 8 + h16 * 4;
      f32x4 bv = *(const f32x4*)(bias + oc0);
      float v[4];
#pragma unroll
      for (int j = 0; j < 4; j++) {
        float s = acc[g * 4 + j] + bv[j];
        v[j] = s >= 0.f ? s : alpha * s;
      }
      uint2 pk;
      pk.x = (unsigned)f2bf(v[0]) | ((unsigned)f2bf(v[1]) << 16);
      pk.y = (unsigned)f2bf(v[2]) | ((unsigned)f2bf(v[3]) << 16);
      size_t idx16 = ((size_t)orow * 4 + g) * PW + ocol;
      o2[idx16 * 2 + h16] = pk;
    }
    __syncthreads();
    if (k < 7) load_rows(rb + 8, 2);
  }
}

// ---- fused 3-head conv 32->16(12 real): strip-marching, gload16 staging ----
__global__ __launch_bounds__(256, 2) void k_headm(const unsigned short* __restrict__ in,
                                                  const unsigned short* __restrict__ wp,
                                                  const float* __restrict__ hb0,
                                                  const float* __restrict__ hb1,
                                                  const float* __restrict__ hb2,
                                                  unsigned short* __restrict__ pre,
                                                  float* __restrict__ S) {
  __shared__ __align__(16) short lds[8 * 4 * 68 * 8];  // 34816 B
  __shared__ float part[4][4][4];
  const int tid = threadIdx.x, lane = tid & 63, wid = tid >> 6;
  const int l15 = lane & 15, q = lane >> 4;
  const int c0 = blockIdx.x * 64;
  const int R0 = blockIdx.y * 32;
  const uint4* in4 = (const uint4*)(in + (size_t)blockIdx.z * PS1);
  float* Sz = S + blockIdx.z * 16;
  uint4* lds4 = (uint4*)lds;

  bf16x8 af[9];
#pragma unroll
  for (int k9 = 0; k9 < 9; k9++)
    af[k9] = *(const bf16x8*)(wp + (size_t)(k9 * 16 + l15) * 32 + q * 8);

  float bs[4];
#pragma unroll
  for (int r = 0; r < 4; r++) {
    int oc = q * 4 + r;
    bs[r] = oc < 4 ? hb0[oc] : (oc < 8 ? hb1[oc - 4] : (oc < 12 ? hb2[oc - 8] : 0.f));
  }
  unsigned short* prehq = pre + ((size_t)(q * 4 + blockIdx.z) * HWSZ) * 4;

  auto load_rows = [&](int rfirst, int nrows) {
    int nseg = nrows * 4;
    for (int sg = wid; sg < nseg; sg += 4) {
      int rr = rfirst + (sg >> 2);
      int ch = sg & 3;
      const uint4* src = in4 + (size_t)(rr * 4 + ch) * PW + c0;
      uint4* dst = lds4 + ((rr & 7) * 4 + ch) * 68;
      gload16(src + lane, dst);
      gload16(src + 4 + lane, dst + 4);
    }
  };

  load_rows(R0, 6);
  float csum[4] = {0.f, 0.f, 0.f, 0.f};

  for (int k = 0; k < 8; ++k) {
    const int rb = R0 + 4 * k;
    __syncthreads();
    if (k < 7) load_rows(rb + 6, 2);

    f32x4 acc[4];
#pragma unroll
    for (int nt = 0; nt < 4; nt++)
#pragma unroll
      for (int j = 0; j < 4; j++) acc[nt][j] = 0.f;

#pragma unroll
    for (int dh = 0; dh < 3; dh++) {
      const short* lrow = lds + (size_t)(((rb + wid + dh) & 7) * 4) * 68 * 8;
#pragma unroll
      for (int dw = 0; dw < 3; dw++) {
        bf16x8 a = af[dh * 3 + dw];
#pragma unroll
        for (int nt = 0; nt < 4; nt++) {
          int pl = nt * 16 + l15 + dw;
          bf16x8 b = *(const bf16x8*)(lrow + (q * 68 + pl) * 8);
          acc[nt] = __builtin_amdgcn_mfma_f32_16x16x32_bf16(a, b, acc[nt], 0, 0, 0);
        }
      }
    }

    const int orow = rb + wid;
#pragma unroll
    for (int nt = 0; nt < 4; nt++) {
      int pix = orow * 512 + c0 + nt * 16 + l15;
      float v[4];
#pragma unroll
      for (int r = 0; r < 4; r++) {
        v[r] = acc[nt][r] + bs[r];
        csum[r] += v[r];
      }
      uint2 pk;
      pk.x = (unsigned)f2bf(v[0]) | ((unsigned)f2bf(v[1]) << 16);
      pk.y = (unsigned)f2bf(v[2]) | ((unsigned)f2bf(v[3]) << 16);
      *(uint2*)(prehq + (size_t)pix * 4) = pk;
    }
    __syncthreads();
    if (k < 7) load_rows(rb + 8, 2);
  }

#pragma unroll
  for (int d = 1; d < 16; d <<= 1)
#pragma unroll
    for (int r = 0; r < 4; r++) csum[r] += __shfl_xor(csum[r], d, 64);
  if (l15 == 0)
#pragma unroll
    for (int r = 0; r < 4; r++) part[wid][q][r] = csum[r];
  __syncthreads();
  if (tid < 12) {
    int oc = tid;
    float s = part[0][oc >> 2][oc & 3] + part[1][oc >> 2][oc & 3] +
              part[2][oc >> 2][oc & 3] + part[3][oc >> 2][oc & 3];
    atomicAdd(&Sz[oc], s);
  }
}

// ---- fused: gate + 3 box blurs + softmax(gate*pre) + weighted combine (z = 8 images) ----
#define BT 32
#define RAD 12
#define SRCT (BT + 2 * RAD)  // 56
__global__ __launch_bounds__(256) void k_blurcombine(const float* __restrict__ src,
                                                     const unsigned short* __restrict__ preA,
                                                     const unsigned short* __restrict__ preB,
                                                     const float* __restrict__ S4,
                                                     const float* __restrict__ wa,
                                                     const float* __restrict__ wb,
                                                     float* __restrict__ dst) {
  __shared__ float tile[SRCT][SRCT];
  __shared__ float hs[3][SRCT][BT];
  __shared__ float g[4];
  const int z = blockIdx.z;
  const float* srcz = src + (size_t)z * HWSZ;
  const unsigned short* prez = (z < 4) ? preA + (size_t)z * HWSZ * 4
                                       : preB + (size_t)(z - 4) * HWSZ * 4;
  const float* S4z = S4 + (z >> 2) * 64 + (z & 3) * 16;
  float* dstz = dst + (size_t)z * HWSZ;
  int h0 = blockIdx.y * BT - RAD, w0 = blockIdx.x * BT - RAD;
  if (threadIdx.x < 4) {
    int o = threadIdx.x;
    float m[4], ga[4];
#pragma unroll
    for (int c = 0; c < 4; c++) m[c] = S4z[c] * (1.0f / (float)HWSZ);
#pragma unroll
    for (int c = 0; c < 4; c++) {
      float s = 0.f;
#pragma unroll
      for (int j = 0; j < 4; j++) s = fmaf(wa[c * 4 + j], m[j], s);
      ga[c] = fmaxf(s, 0.f);
    }
    float s2 = 0.f;
#pragma unroll
    for (int c = 0; c < 4; c++) s2 = fmaf(wb[o * 4 + c], ga[c], s2);
    g[o] = 1.f / (1.f + expf(-s2));
  }
  for (int idx = threadIdx.x; idx < SRCT * SRCT; idx += 256) {
    int r = idx / SRCT, c = idx % SRCT;
    int hh = h0 + r, ww = w0 + c;
    float v = 0.f;
    if (hh >= 0 && hh < HH && ww >= 0 && ww < WW) v = srcz[hh * WW + ww];
    tile[r][c] = v;
  }
  __syncthreads();
  for (int idx = threadIdx.x; idx < SRCT * BT; idx += 256) {
    int r = idx / BT, j = idx % BT;
    int cc = j + RAD;
    float s5 = 0.f;
#pragma unroll
    for (int d = -2; d <= 2; d++) s5 += tile[r][cc + d];
    float s15 = s5;
#pragma unroll
    for (int d = 3; d <= 7; d++) s15 += tile[r][cc + d] + tile[r][cc - d];
    float s25 = s15;
#pragma unroll
    for (int d = 8; d <= 12; d++) s25 += tile[r][cc + d] + tile[r][cc - d];
    hs[0][r][j] = s5;
    hs[1][r][j] = s15;
    hs[2][r][j] = s25;
  }
  __syncthreads();
  for (int p = threadIdx.x; p < BT * BT; p += 256) {
    int i = p / BT, j = p % BT;
    int rr = i + RAD;
    float b1 = 0.f;
#pragma unroll
    for (int d = -2; d <= 2; d++) b1 += hs[0][rr + d][j];
    float b2 = 0.f;
#pragma unroll
    for (int d = -7; d <= 7; d++) b2 += hs[1][rr + d][j];
    float b3 = 0.f;
#pragma unroll
    for (int d = -12; d <= 12; d++) b3 += hs[2][rr + d][j];
    b1 *= (1.f / 25.f);
    b2 *= (1.f / 225.f);
    b3 *= (1.f / 625.f);
    float b0 = tile[rr][j + RAD];
    int y = blockIdx.y * BT + i, x = blockIdx.x * BT + j;
    int pix = y * WW + x;
    uint2 pk = *(const uint2*)(prez + (size_t)pix * 4);
    float v[4];
    v[0] = bf2f(pk.x & 0xffffu) * g[0];
    v[1] = bf2f(pk.x >> 16) * g[1];
    v[2] = bf2f(pk.y & 0xffffu) * g[2];
    v[3] = bf2f(pk.y >> 16) * g[3];
    float mx = fmaxf(fmaxf(v[0], v[1]), fmaxf(v[2], v[3]));
    float e0 = expf(v[0] - mx), e1 = expf(v[1] - mx), e2 = expf(v[2] - mx),
          e3 = expf(v[3] - mx);
    float inv = 1.f / (e0 + e1 + e2 + e3);
    dstz[pix] = (e0 * b0 + e1 * b1 + e2 * b2 + e3 * b3) * inv;
  }
}

extern "C" void kernel_launch(void* const* d_in, const int* in_sizes, int n_in,
                              void* d_out, int out_size, void* d_ws, size_t ws_size,
                              hipStream_t stream) {
  const float* x = (const float*)d_in[0];
  const float* w1 = (const float*)d_in[1];
  const float* b1 = (const float*)d_in[2];
  const float* a1 = (const float*)d_in[3];
  const float* w2 = (const float*)d_in[4];
  const float* b2 = (const float*)d_in[5];
  const float* a2 = (const float*)d_in[6];
  const float* w3 = (const float*)d_in[7];
  const float* b3 = (const float*)d_in[8];
  const float* a3 = (const float*)d_in[9];
  const float* hw[3] = {(const float*)d_in[10], (const float*)d_in[14], (const float*)d_in[18]};
  const float* hb[3] = {(const float*)d_in[11], (const float*)d_in[15], (const float*)d_in[19]};
  const float* caa[3] = {(const float*)d_in[12], (const float*)d_in[16], (const float*)d_in[20]};
  const float* cab[3] = {(const float*)d_in[13], (const float*)d_in[17], (const float*)d_in[21]};

  char* base = (char*)d_ws;
  size_t off = 0;
  auto alloc = [&](size_t bytes) {
    char* p = base + off;
    off = (off + bytes + 63) & ~(size_t)63;
    return p;
  };
  unsigned short* t1 = (unsigned short*)alloc(4 * PS1 * 2);          // 67.9 MB
  unsigned short* t2 = (unsigned short*)alloc(4 * PS2 * 2);          // 135.8 MB
  unsigned short* pre = (unsigned short*)alloc(16 * (size_t)HWSZ * 4 * 2);  // 32 MB (group 0)
  unsigned short* wp2 = (unsigned short*)alloc(9 * 64 * 32 * 2);
  unsigned short* wp3 = (unsigned short*)alloc(9 * 64 * 32 * 2);
  unsigned short* wph = (unsigned short*)alloc(9 * 16 * 32 * 2);
  float* out1 = (float*)alloc(8 * (size_t)HWSZ * 4);                 // 8.4 MB (8 images)
  float* out2 = (float*)alloc(8 * (size_t)HWSZ * 4);                 // 8.4 MB
  float* S = (float*)alloc(8 * 16 * 4);
  // group-1 pre aliases t2 (t2 is dead after conv3-g1; serial stream makes this safe)
  unsigned short* pre2 = t2;

  dim3 blk(256);
  {
    int total = 9 * 64 * 32 + 9 * 32 * 64 + 9 * 16 * 32 + 4 * NZ1 + 4 * NZ2 + 128;
    k_prep<<<(total + 255) / 256, blk, 0, stream>>>(w2, w3, hw[0], hw[1], hw[2], wp2,
                                                    wp3, wph, t1, t2, S);
  }

  dim3 gc1(1024, 1, 4);
  dim3 gconv(8, 16, 4);     // 64-col strips x 32-row chunks x 4 images
  dim3 gconv3(16, 16, 4);   // 32-col strips x 32-row chunks x 4 images
  dim3 gbc8(WW / BT, HH / BT, 8);
  const size_t preplane = (size_t)HWSZ * 4;  // shorts per [head][image] plane
  for (int g = 0; g < 2; g++) {
    const float* xg = x + (size_t)g * 4 * HWSZ;
    float* Sg = S + g * 64;
    unsigned short* preg = g ? pre2 : pre;
    k_conv1<<<gc1, blk, 0, stream>>>(xg, w1, b1, a1, t1);
    k_convm2<<<gconv, blk, 0, stream>>>(t1, wp2, b2, a2, t2);
    k_convm3<<<gconv3, blk, 0, stream>>>(t2, wp3, b3, a3, t1);
    k_headm<<<gconv, blk, 0, stream>>>(t1, wph, hb[0], hb[1], hb[2], preg, Sg);
  }
  // batched blur chain: all 8 images per launch (pre2-g1 written after t2's last read)
  k_blurcombine<<<gbc8, blk, 0, stream>>>(x, pre + 0 * 4 * preplane,
                                          pre2 + 0 * 4 * preplane, S + 0, caa[0],
                                          cab[0], out1);
  k_blurcombine<<<gbc8, blk, 0, stream>>>(out1, pre + 1 * 4 * preplane,
                                          pre2 + 1 * 4 * preplane, S + 4, caa[1],
                                          cab[1], out2);
  k_blurcombine<<<gbc8, blk, 0, stream>>>(out2, pre + 2 * 4 * preplane,
                                          pre2 + 2 * 4 * preplane, S + 8, caa[2],
                                          cab[2], (float*)d_out);
}